// Round 12
// baseline (1530.799 us; speedup 1.0000x reference)
//
#include <hip/hip_runtime.h>
#include <hip/hip_bf16.h>
#include <math.h>

#define NODE 90
#define HID 256
#define NB 512
#define NN (NB * NODE)
#define EDGES (NB * 2700)

typedef __attribute__((ext_vector_type(8))) short bf16x8;
typedef __attribute__((ext_vector_type(4))) float f32x4;

__device__ __forceinline__ float tanh_safe(float s) {
    s = fminf(fmaxf(s, -15.f), 15.f);
    float t = __expf(2.f * s);
    return (t - 1.f) / (t + 1.f);
}

// bf16 RNE via bit trick; inputs finite.
__device__ __forceinline__ unsigned short f2b(float x) {
    unsigned u = __float_as_uint(x);
    return (unsigned short)((u + 0x7FFFu + ((u >> 16) & 1u)) >> 16);
}
__device__ __forceinline__ float b2f(unsigned short h) {
    return __uint_as_float(((unsigned)h) << 16);
}

// ---------------------------------------------------------------------------
// Module-scope fp32 scratch. d_ws unused.
// ---------------------------------------------------------------------------
__device__ float g_adjS[(size_t)NB * NODE * NODE];
__device__ float g_adjF[(size_t)NB * NODE * NODE];
__device__ float g_T[(size_t)2 * NN * HID];          // 2N rows (S then F)
__device__ float g_hs[(size_t)NN * HID];
__device__ float g_hf[(size_t)NN * HID];
__device__ float g_cs[(size_t)NN * HID];
__device__ float g_cf[(size_t)NN * HID];
__device__ int g_flags[2];

__device__ __forceinline__ float* adjPtr(int w) { return w ? g_adjF : g_adjS; }
__device__ __forceinline__ float* selbuf(int w) {
    switch (w) {
        case 0: return g_hs;
        case 1: return g_hf;
        case 2: return g_cs;
        default: return g_cf;
    }
}

// ---------------------------------------------------------------------------
__global__ void k_detect(const void* edges) {
    if (threadIdx.x != 0 || blockIdx.x != 0) return;
    const int* ei = (const int*)edges;
    int odd_nonzero = 0;
    for (int i = 0; i < 2048; i += 2)
        if (ei[i + 1] != 0) odd_nonzero = 1;
    g_flags[1] = odd_nonzero ? 0 : 1;
}

__global__ void k_zero_adj() {
    size_t n = (size_t)NB * NODE * NODE;
    size_t stride = (size_t)gridDim.x * blockDim.x;
    for (size_t i = (size_t)blockIdx.x * blockDim.x + threadIdx.x; i < n; i += stride) {
        g_adjS[i] = 0.f;
        g_adjF[i] = 0.f;
    }
}

// ---------------------------------------------------------------------------
__global__ void k_build_adj(const void* __restrict__ edges, int which) {
    float* adj = adjPtr(which);
    int e64 = g_flags[1];
    const int* e32 = (const int*)edges;
    const long long* e64p = (const long long*)edges;
    int i = blockIdx.x * blockDim.x + threadIdx.x;
    int stride = gridDim.x * blockDim.x;
    for (; i < EDGES; i += stride) {
        long long s, d;
        if (e64) { s = e64p[i]; d = e64p[EDGES + i]; }
        else     { s = e32[i];  d = e32[EDGES + i]; }
        if (s < 0 || s >= NN || d < 0 || d >= NN) continue;
        int b = (int)(d / NODE);
        if ((int)(s / NODE) != b) continue;
        atomicAdd(&adj[(size_t)b * NODE * NODE +
                       (size_t)((int)d - b * NODE) * NODE + ((int)s - b * NODE)], 1.0f);
    }
}

// ---------------------------------------------------------------------------
__global__ void k_norm_adj(int which) {
    float* A = adjPtr(which) + (size_t)blockIdx.x * NODE * NODE;
    __shared__ float dinv[NODE];
    int tid = threadIdx.x;
    if (tid < NODE) {
        float s = 0.f;
        for (int k = 0; k < NODE; k++) s += A[tid * NODE + k];
        dinv[tid] = (s > 0.f) ? rsqrtf(s) : 0.f;
    }
    __syncthreads();
    for (int i = tid; i < NODE * NODE; i += blockDim.x) {
        int d = i / NODE;
        int s = i - d * NODE;
        A[i] *= dinv[d] * dinv[s];
    }
}

// ---------------------------------------------------------------------------
// MFMA bf16x2-split GEMM: g_T[tbase+r][c] = X(r,:) @ W, fp32-grade accuracy.
//   x = hi + lo (both bf16); acc += hi*hi + hi*lo + lo*hi  (ll dropped, 2^-16)
// Tile 64x64, K-step 32, 256 threads (4 waves); wave w = rows 16w..16w+15.
// LDS: A [row][k] stride 40 ushorts; B transposed-on-store [col][k] stride 40.
// Frag A: lane l -> row l&15, k = 8*(l>>4)+j (ds_read_b128, conflict-free).
// ---------------------------------------------------------------------------
#define GK 32
#define ASTR 40
__global__ __launch_bounds__(256) void k_gemm_mfma(const float* __restrict__ Xext,
                                                   int x1sel, int x2sel,
                                                   int K, int ldx_ext,
                                                   const float* __restrict__ W,
                                                   int tbase) {
    __shared__ unsigned short Ah[64][ASTR], Al[64][ASTR];
    __shared__ unsigned short Bh[64][ASTR], Bl[64][ASTR];
    int tid = threadIdx.x;
    int id = blockIdx.x;
    int bn = id & 3, bm = id >> 2;
    int r0 = bm * 64, c0 = bn * 64;
    const float* X1 = (x1sel >= 0) ? selbuf(x1sel) : Xext;
    const float* X2 = (x2sel >= 0) ? selbuf(x2sel) : nullptr;
    int ldx = (x1sel >= 0) ? HID : ldx_ext;

    int w = tid >> 6;       // wave
    int l = tid & 63;       // lane
    int lr = l & 15;
    int lq = l >> 4;        // 0..3
    int koff = lq * 8;

    f32x4 acc[4];
#pragma unroll
    for (int c = 0; c < 4; c++) acc[c] = (f32x4){0.f, 0.f, 0.f, 0.f};

    int nt = (K + GK - 1) / GK;
    for (int t = 0; t < nt; t++) {
        int k0 = t * GK;
        int kl = K - k0; if (kl > GK) kl = GK;
        const float* Xs; int xc;
        if (x2sel >= 0 && k0 >= HID) { Xs = X2; xc = k0 - HID; }
        else                          { Xs = X1; xc = k0; }

        __syncthreads();
        // stage A: 64 rows x 32 k; task = (row, even-k-pair); coalesced reads
#pragma unroll
        for (int q = 0; q < 4; q++) {
            int i = tid + (q << 8);
            int r = i >> 4;
            int kp = (i & 15) << 1;
            float x0 = (kp < kl)     ? Xs[(size_t)(r0 + r) * ldx + xc + kp]     : 0.f;
            float x1 = (kp + 1 < kl) ? Xs[(size_t)(r0 + r) * ldx + xc + kp + 1] : 0.f;
            unsigned short h0 = f2b(x0), h1 = f2b(x1);
            unsigned short l0 = f2b(x0 - b2f(h0)), l1 = f2b(x1 - b2f(h1));
            *(unsigned*)&Ah[r][kp] = (unsigned)h0 | ((unsigned)h1 << 16);
            *(unsigned*)&Al[r][kp] = (unsigned)l0 | ((unsigned)l1 << 16);
        }
        // stage B transposed: task = (col n, even-k-pair); reads coalesced over n
#pragma unroll
        for (int q = 0; q < 4; q++) {
            int i = tid + (q << 8);
            int n = i & 63;
            int kp = (i >> 6) << 1;
            float x0 = (kp < kl)     ? W[(size_t)(k0 + kp) * HID + c0 + n]     : 0.f;
            float x1 = (kp + 1 < kl) ? W[(size_t)(k0 + kp + 1) * HID + c0 + n] : 0.f;
            unsigned short h0 = f2b(x0), h1 = f2b(x1);
            unsigned short l0 = f2b(x0 - b2f(h0)), l1 = f2b(x1 - b2f(h1));
            *(unsigned*)&Bh[n][kp] = (unsigned)h0 | ((unsigned)h1 << 16);
            *(unsigned*)&Bl[n][kp] = (unsigned)l0 | ((unsigned)l1 << 16);
        }
        __syncthreads();

        bf16x8 ah = *(const bf16x8*)&Ah[16 * w + lr][koff];
        bf16x8 al = *(const bf16x8*)&Al[16 * w + lr][koff];
#pragma unroll
        for (int c = 0; c < 4; c++) {
            bf16x8 bh = *(const bf16x8*)&Bh[16 * c + lr][koff];
            bf16x8 bl = *(const bf16x8*)&Bl[16 * c + lr][koff];
            acc[c] = __builtin_amdgcn_mfma_f32_16x16x32_bf16(ah, bh, acc[c], 0, 0, 0);
            acc[c] = __builtin_amdgcn_mfma_f32_16x16x32_bf16(ah, bl, acc[c], 0, 0, 0);
            acc[c] = __builtin_amdgcn_mfma_f32_16x16x32_bf16(al, bh, acc[c], 0, 0, 0);
        }
    }

    // D: col = c0+16c+lr, row = r0+16w+4*lq+qq
#pragma unroll
    for (int c = 0; c < 4; c++) {
#pragma unroll
        for (int qq = 0; qq < 4; qq++) {
            size_t row = (size_t)(tbase + r0 + 16 * w + 4 * lq + qq);
            g_T[row * HID + c0 + 16 * c + lr] = acc[c][qq];
        }
    }
}

// ---------------------------------------------------------------------------
// Fused two-stream aggregate (unchanged — verified).
// ---------------------------------------------------------------------------
__global__ __launch_bounds__(256) void k_agg2(const float* __restrict__ bias,
                                              int hsel0, float* __restrict__ outS,
                                              float* __restrict__ outF) {
    __shared__ float AdjT[NODE][102];
    int tid = threadIdx.x;
    int idx = blockIdx.x;
    int side = idx >> 10;
    int b = (idx & 1023) >> 1;
    int c0 = (idx & 1) * 128;
    const float* Adj = adjPtr(side) + (size_t)b * NODE * NODE;
    const float* Tg = g_T + ((size_t)side * NN + (size_t)b * NODE) * HID;
    float* outp = side ? outF : outS;
    float* hdst = selbuf(hsel0 + side);

    for (int i = tid; i < NODE * NODE; i += 256) {
        int n = i / NODE, k = i - n * NODE;
        AdjT[k][n] = Adj[i];
    }
    for (int i = tid; i < NODE * 12; i += 256) {
        int k = i / 12, n = NODE + (i % 12);
        AdjT[k][n] = 0.f;
    }
    __syncthreads();

    int ti = tid & 15, tj = tid >> 4;
    int rbase = 6 * ti;
    int cc = c0 + 8 * tj;

    float acc[6][8];
#pragma unroll
    for (int i = 0; i < 6; i++)
#pragma unroll
        for (int j = 0; j < 8; j++) acc[i][j] = 0.f;

#pragma unroll 2
    for (int k = 0; k < NODE; k++) {
        float4 t0 = *(const float4*)&Tg[(size_t)k * HID + cc];
        float4 t1 = *(const float4*)&Tg[(size_t)k * HID + cc + 4];
        float bv[8] = {t0.x, t0.y, t0.z, t0.w, t1.x, t1.y, t1.z, t1.w};
        float2 a01 = *(const float2*)&AdjT[k][rbase];
        float2 a23 = *(const float2*)&AdjT[k][rbase + 2];
        float2 a45 = *(const float2*)&AdjT[k][rbase + 4];
        float av[6] = {a01.x, a01.y, a23.x, a23.y, a45.x, a45.y};
#pragma unroll
        for (int i = 0; i < 6; i++)
#pragma unroll
            for (int j = 0; j < 8; j++)
                acc[i][j] = fmaf(av[i], bv[j], acc[i][j]);
    }

    float bb[8];
#pragma unroll
    for (int j = 0; j < 8; j++) bb[j] = bias[cc + j];

#pragma unroll
    for (int i = 0; i < 6; i++) {
        int n = rbase + i;
        if (n < NODE) {
            size_t row = (size_t)(b * NODE + n);
            float v[8];
#pragma unroll
            for (int j = 0; j < 8; j++) v[j] = fmaxf(acc[i][j] + bb[j], 0.f);
            float4 o0 = make_float4(v[0], v[1], v[2], v[3]);
            float4 o1 = make_float4(v[4], v[5], v[6], v[7]);
            *(float4*)&hdst[row * HID + cc] = o0;
            *(float4*)&hdst[row * HID + cc + 4] = o1;
            *(float4*)&outp[row * 512 + cc] = o0;
            *(float4*)&outp[row * 512 + cc + 4] = o1;
        }
    }
}

// ---------------------------------------------------------------------------
// Fused co-attention per graph (unchanged — verified).
// ---------------------------------------------------------------------------
#define CO_THREADS 512
__global__ __launch_bounds__(CO_THREADS, 1) void k_coatt(int hfsel, int hssel,
                                                         float* __restrict__ outS,
                                                         float* __restrict__ outF,
                                                         int cssel, int cfsel) {
    __shared__ float hfl[NODE][258];
    __shared__ float Pm[NODE][92];
    __shared__ float t2s[NODE][34];
    __shared__ float rmax_[NODE], rinv_[NODE], fn_[NODE], gm_[NODE];

    int b = blockIdx.x;
    int tid = threadIdx.x;
    const float* HF = selbuf(hfsel) + (size_t)b * NODE * HID;
    const float* HS = selbuf(hssel) + (size_t)b * NODE * HID;
    const float* T2 = g_T + (size_t)b * NODE * HID;

    for (int i = tid; i < NODE * 64; i += CO_THREADS) {
        int n = i >> 6, c4 = (i & 63) << 2;
        *(float4*)&hfl[n][c4] = *(const float4*)&HF[(size_t)n * HID + c4];
    }

    {
        const int tm = tid & 31;
        const int tn5 = tid >> 5;
        const float* hr0 = hfl[tm];
        const float* hr1 = hfl[tm + 32];
        const float* hr2 = hfl[(tm < 26) ? tm + 64 : 0];
        const float* tr[6];
#pragma unroll
        for (int k = 0; k < 6; k++) {
            int n = tn5 + 16 * k;
            tr[k] = t2s[(n < NODE) ? n : 0];
        }
        float at[3][6];
#pragma unroll
        for (int i = 0; i < 3; i++)
#pragma unroll
            for (int k = 0; k < 6; k++) at[i][k] = 0.f;

        for (int d0 = 0; d0 < HID; d0 += 32) {
            __syncthreads();
            for (int i = tid; i < NODE * 32; i += CO_THREADS) {
                int n = i >> 5, dd = i & 31;
                t2s[n][dd] = T2[(size_t)n * HID + d0 + dd];
            }
            __syncthreads();
#pragma unroll
            for (int dd = 0; dd < 32; dd += 2) {
                float2 a0 = *(const float2*)&hr0[d0 + dd];
                float2 a1 = *(const float2*)&hr1[d0 + dd];
                float2 a2 = *(const float2*)&hr2[d0 + dd];
#pragma unroll
                for (int k = 0; k < 6; k++) {
                    float2 bk = *(const float2*)&tr[k][dd];
                    at[0][k] = fmaf(a0.x, bk.x, at[0][k]);
                    at[0][k] = fmaf(a0.y, bk.y, at[0][k]);
                    at[1][k] = fmaf(a1.x, bk.x, at[1][k]);
                    at[1][k] = fmaf(a1.y, bk.y, at[1][k]);
                    at[2][k] = fmaf(a2.x, bk.x, at[2][k]);
                    at[2][k] = fmaf(a2.y, bk.y, at[2][k]);
                }
            }
        }
        __syncthreads();
        int mv[3] = {tm, tm + 32, tm + 64};
#pragma unroll
        for (int i = 0; i < 3; i++) {
            if (mv[i] < NODE) {
#pragma unroll
                for (int k = 0; k < 6; k++) {
                    int n = tn5 + 16 * k;
                    if (n < NODE) Pm[n][mv[i]] = tanh_safe(at[i][k]);
                }
            }
        }
    }
    __syncthreads();

    if (tid < NODE) {
        int n = tid;
        float mx = -2.f;
        for (int m = 0; m < NODE; m++) mx = fmaxf(mx, Pm[n][m]);
        float s = 0.f;
        for (int m = 0; m < NODE; m++) s += __expf(Pm[n][m] - mx);
        rmax_[n] = mx;
        rinv_[n] = 1.f / s;
        fn_[n] = s * __expf(mx);
    } else if (tid >= 256 && tid < 256 + NODE) {
        int m = tid - 256;
        float mx = -2.f;
        for (int n = 0; n < NODE; n++) mx = fmaxf(mx, Pm[n][m]);
        float s = 0.f;
        for (int n = 0; n < NODE; n++) s += __expf(Pm[n][m] - mx);
        gm_[m] = __expf(-mx) / s;
    }
    __syncthreads();

    for (int i = tid; i < NODE * NODE; i += CO_THREADS) {
        int n = i / NODE, m = i - n * NODE;
        Pm[n][m] = __expf(Pm[n][m] - rmax_[n]) * rinv_[n];
    }
    __syncthreads();

    {
        const int tc4 = (tid & 63) << 2;
        const int tnn = tid >> 6;
        int nrow[12];
#pragma unroll
        for (int k = 0; k < 12; k++) {
            int n = tnn + 8 * k;
            nrow[k] = (n < NODE) ? n : 0;
        }
        float acc[12][4];
#pragma unroll
        for (int k = 0; k < 12; k++)
#pragma unroll
            for (int j = 0; j < 4; j++) acc[k][j] = 0.f;

#pragma unroll 2
        for (int m = 0; m < NODE; m++) {
            float4 h = *(const float4*)&hfl[m][tc4];
#pragma unroll
            for (int k = 0; k < 12; k++) {
                float p = Pm[nrow[k]][m];
                acc[k][0] = fmaf(p, h.x, acc[k][0]);
                acc[k][1] = fmaf(p, h.y, acc[k][1]);
                acc[k][2] = fmaf(p, h.z, acc[k][2]);
                acc[k][3] = fmaf(p, h.w, acc[k][3]);
            }
        }
        float* cs = selbuf(cssel);
#pragma unroll
        for (int k = 0; k < 12; k++) {
            int n = tnn + 8 * k;
            if (n < NODE) {
                size_t row = (size_t)(b * NODE + n);
                float4 o = make_float4(acc[k][0], acc[k][1], acc[k][2], acc[k][3]);
                *(float4*)&outS[row * 512 + tc4] = o;
                *(float4*)&cs[row * HID + tc4] = o;
            }
        }
    }
    __syncthreads();

    for (int i = tid; i < NODE * 64; i += CO_THREADS) {
        int n = i >> 6, c4 = (i & 63) << 2;
        *(float4*)&hfl[n][c4] = *(const float4*)&HS[(size_t)n * HID + c4];
    }
    for (int i = tid; i < NODE * NODE; i += CO_THREADS) {
        int n = i / NODE, m = i - n * NODE;
        Pm[n][m] *= fn_[n];
    }
    __syncthreads();

    {
        const int tc4 = (tid & 63) << 2;
        const int tmm = tid >> 6;
        int mrow[12];
#pragma unroll
        for (int k = 0; k < 12; k++) {
            int m = tmm + 8 * k;
            mrow[k] = (m < NODE) ? m : 0;
        }
        float acc[12][4];
#pragma unroll
        for (int k = 0; k < 12; k++)
#pragma unroll
            for (int j = 0; j < 4; j++) acc[k][j] = 0.f;

#pragma unroll 2
        for (int n = 0; n < NODE; n++) {
            float4 h = *(const float4*)&hfl[n][tc4];
#pragma unroll
            for (int k = 0; k < 12; k++) {
                float p = Pm[n][mrow[k]];
                acc[k][0] = fmaf(p, h.x, acc[k][0]);
                acc[k][1] = fmaf(p, h.y, acc[k][1]);
                acc[k][2] = fmaf(p, h.z, acc[k][2]);
                acc[k][3] = fmaf(p, h.w, acc[k][3]);
            }
        }
        float* cf = selbuf(cfsel);
#pragma unroll
        for (int k = 0; k < 12; k++) {
            int m = tmm + 8 * k;
            if (m < NODE) {
                float g = gm_[m];
                size_t row = (size_t)(b * NODE + m);
                float4 o = make_float4(acc[k][0] * g, acc[k][1] * g,
                                       acc[k][2] * g, acc[k][3] * g);
                *(float4*)&outF[row * 512 + tc4] = o;
                *(float4*)&cf[row * HID + tc4] = o;
            }
        }
    }
}

// ---------------------------------------------------------------------------
extern "C" void kernel_launch(void* const* d_in, const int* in_sizes, int n_in,
                              void* d_out, int out_size, void* d_ws, size_t ws_size,
                              hipStream_t stream) {
    const float* x_sc = (const float*)d_in[0];
    const void* e_sc = d_in[1];
    const float* x_fc = (const float*)d_in[2];
    const void* e_fc = d_in[3];
    const float* W0 = (const float*)d_in[4];
    const float* b0 = (const float*)d_in[5];
    const float* W1 = (const float*)d_in[6];
    const float* b1 = (const float*)d_in[7];
    const float* Wa = (const float*)d_in[8];

    float* out = (float*)d_out;
    size_t os = (size_t)NN * 512;
    float* x1s = out;
    float* x2s = out + os;
    float* x1f = out + 2 * os;
    float* x2f = out + 3 * os;

    const int GRID = (NN / 64) * 4;       // 2880 blocks per GEMM dispatch

    k_detect<<<1, 64, 0, stream>>>(e_sc);
    k_zero_adj<<<2048, 256, 0, stream>>>();
    k_build_adj<<<1024, 256, 0, stream>>>(e_sc, 0);
    k_build_adj<<<1024, 256, 0, stream>>>(e_fc, 1);
    k_norm_adj<<<NB, 128, 0, stream>>>(0);
    k_norm_adj<<<NB, 128, 0, stream>>>(1);

    // ---- layer 1: T_S = x_sc @ W0, T_F = x_fc @ W0 (K=90) ----
    k_gemm_mfma<<<GRID, 256, 0, stream>>>(x_sc, -1, -1, NODE, NODE, W0, 0);
    k_gemm_mfma<<<GRID, 256, 0, stream>>>(x_fc, -1, -1, NODE, NODE, W0, NN);
    k_agg2<<<2048, 256, 0, stream>>>(b0, /*hs/hf*/0, x1s, x1f);

    // ---- co-attention 1: T2 = hs @ Wa (K=256) ----
    k_gemm_mfma<<<GRID, 256, 0, stream>>>(nullptr, 0, -1, HID, HID, Wa, 0);
    k_coatt<<<NB, CO_THREADS, 0, stream>>>(/*hf*/1, /*hs*/0, x1s + HID, x1f + HID, 2, 3);

    // ---- layer 2: T_S = [hs|cs] @ W1, T_F = [hf|cf] @ W1 (K=512) ----
    k_gemm_mfma<<<GRID, 256, 0, stream>>>(nullptr, 0, 2, 512, HID, W1, 0);
    k_gemm_mfma<<<GRID, 256, 0, stream>>>(nullptr, 1, 3, 512, HID, W1, NN);
    k_agg2<<<2048, 256, 0, stream>>>(b1, /*hs2/hf2*/0, x2s, x2f);

    // ---- co-attention 2 ----
    k_gemm_mfma<<<GRID, 256, 0, stream>>>(nullptr, 0, -1, HID, HID, Wa, 0);
    k_coatt<<<NB, CO_THREADS, 0, stream>>>(/*hf2*/1, /*hs2*/0, x2s + HID, x2f + HID, 2, 3);
}

// Round 13
// 1206.672 us; speedup vs baseline: 1.2686x; 1.2686x over previous
//
#include <hip/hip_runtime.h>
#include <hip/hip_bf16.h>
#include <math.h>

#define NODE 90
#define HID 256
#define NB 512
#define NN (NB * NODE)
#define EDGES (NB * 2700)
#define XLD 96            // padded K for layer-1 inputs

typedef __attribute__((ext_vector_type(8))) short bf16x8;
typedef __attribute__((ext_vector_type(4))) float f32x4;

__device__ __forceinline__ float tanh_safe(float s) {
    s = fminf(fmaxf(s, -15.f), 15.f);
    float t = __expf(2.f * s);
    return (t - 1.f) / (t + 1.f);
}

// bf16 RNE via bit trick; inputs finite.
__device__ __forceinline__ unsigned short f2b(float x) {
    unsigned u = __float_as_uint(x);
    return (unsigned short)((u + 0x7FFFu + ((u >> 16) & 1u)) >> 16);
}
__device__ __forceinline__ float b2f(unsigned short h) {
    return __uint_as_float(((unsigned)h) << 16);
}

// ---------------------------------------------------------------------------
// Module-scope scratch. d_ws unused.
// ---------------------------------------------------------------------------
__device__ float g_adjS[(size_t)NB * NODE * NODE];
__device__ float g_adjF[(size_t)NB * NODE * NODE];
__device__ float g_T[(size_t)2 * NN * HID];          // 2N rows (S then F)
__device__ float g_hs[(size_t)NN * HID];
__device__ float g_hf[(size_t)NN * HID];
__device__ float g_cs[(size_t)NN * HID];
__device__ float g_cf[(size_t)NN * HID];
__device__ int g_flags[2];

// bf16 hi/lo planes for MFMA GEMM operands
__device__ unsigned short g_hshi[(size_t)NN * HID], g_hslo[(size_t)NN * HID];
__device__ unsigned short g_hfhi[(size_t)NN * HID], g_hflo[(size_t)NN * HID];
__device__ unsigned short g_cshi[(size_t)NN * HID], g_cslo[(size_t)NN * HID];
__device__ unsigned short g_cfhi[(size_t)NN * HID], g_cflo[(size_t)NN * HID];
__device__ unsigned short g_xshi[(size_t)NN * XLD], g_xslo[(size_t)NN * XLD];
__device__ unsigned short g_xfhi[(size_t)NN * XLD], g_xflo[(size_t)NN * XLD];
__device__ unsigned short g_w0thi[256 * XLD], g_w0tlo[256 * XLD];
__device__ unsigned short g_wathi[256 * 256], g_watlo[256 * 256];
__device__ unsigned short g_w1thi[256 * 512], g_w1tlo[256 * 512];

__device__ __forceinline__ float* adjPtr(int w) { return w ? g_adjF : g_adjS; }
__device__ __forceinline__ float* selbuf(int w) {
    switch (w) {
        case 0: return g_hs;
        case 1: return g_hf;
        case 2: return g_cs;
        default: return g_cf;
    }
}
__device__ __forceinline__ unsigned short* selhi(int w) {
    switch (w) {
        case 0: return g_hshi;
        case 1: return g_hfhi;
        case 2: return g_cshi;
        case 3: return g_cfhi;
        case 4: return g_xshi;
        default: return g_xfhi;
    }
}
__device__ __forceinline__ unsigned short* sello(int w) {
    switch (w) {
        case 0: return g_hslo;
        case 1: return g_hflo;
        case 2: return g_cslo;
        case 3: return g_cflo;
        case 4: return g_xslo;
        default: return g_xflo;
    }
}
__device__ __forceinline__ unsigned short* wthi(int w) {
    switch (w) { case 0: return g_w0thi; case 1: return g_wathi; default: return g_w1thi; }
}
__device__ __forceinline__ unsigned short* wtlo(int w) {
    switch (w) { case 0: return g_w0tlo; case 1: return g_watlo; default: return g_w1tlo; }
}

// ---------------------------------------------------------------------------
__global__ void k_detect(const void* edges) {
    if (threadIdx.x != 0 || blockIdx.x != 0) return;
    const int* ei = (const int*)edges;
    int odd_nonzero = 0;
    for (int i = 0; i < 2048; i += 2)
        if (ei[i + 1] != 0) odd_nonzero = 1;
    g_flags[1] = odd_nonzero ? 0 : 1;
}

// ---------------------------------------------------------------------------
// Fused adjacency: one block per (side, graph). Edges are block-ordered by
// construction (graph b owns indices [b*2700,(b+1)*2700)). Counts in LDS,
// normalize, single write. Guarded: out-of-block edges skipped.
// ---------------------------------------------------------------------------
__global__ __launch_bounds__(256) void k_adj_fused(const void* __restrict__ eS,
                                                   const void* __restrict__ eF) {
    __shared__ float cnt[NODE][NODE + 1];
    __shared__ float dinv[NODE];
    int side = blockIdx.x >> 9;
    int b = blockIdx.x & 511;
    const void* edges = side ? eF : eS;
    int tid = threadIdx.x;
    for (int i = tid; i < NODE * (NODE + 1); i += 256) (&cnt[0][0])[i] = 0.f;
    __syncthreads();
    int e64 = g_flags[1];
    const long long* p64 = (const long long*)edges;
    const int* p32 = (const int*)edges;
    for (int i = tid; i < 2700; i += 256) {
        int idx = b * 2700 + i;
        long long s, d;
        if (e64) { s = p64[idx]; d = p64[EDGES + idx]; }
        else     { s = p32[idx]; d = p32[EDGES + idx]; }
        int sl = (int)s - b * NODE, dl = (int)d - b * NODE;
        if (sl >= 0 && sl < NODE && dl >= 0 && dl < NODE)
            atomicAdd(&cnt[dl][sl], 1.0f);
    }
    __syncthreads();
    if (tid < NODE) {
        float s = 0.f;
        for (int k = 0; k < NODE; k++) s += cnt[tid][k];
        dinv[tid] = (s > 0.f) ? rsqrtf(s) : 0.f;
    }
    __syncthreads();
    float* adj = adjPtr(side) + (size_t)b * NODE * NODE;
    for (int i = tid; i < NODE * NODE; i += 256) {
        int d = i / NODE, s = i - d * NODE;
        adj[i] = cnt[d][s] * dinv[d] * dinv[s];
    }
}

// ---------------------------------------------------------------------------
// Convert layer-1 X [NN][90] fp32 -> hi/lo bf16 planes [NN][96] (zero-pad).
// Task = (row, k-oct). 8 elems -> 16B per plane.
// ---------------------------------------------------------------------------
__global__ void k_convX(const float* __restrict__ X, int side) {
    int t = blockIdx.x * blockDim.x + threadIdx.x;
    if (t >= NN * (XLD / 8)) return;
    int r = t / (XLD / 8), o = t - r * (XLD / 8);
    unsigned short h8[8], l8[8];
#pragma unroll
    for (int j = 0; j < 8; j++) {
        int k = 8 * o + j;
        float x = (k < NODE) ? X[(size_t)r * NODE + k] : 0.f;
        unsigned short h = f2b(x);
        h8[j] = h;
        l8[j] = f2b(x - b2f(h));
    }
    unsigned short* ph = side ? g_xfhi : g_xshi;
    unsigned short* pl = side ? g_xflo : g_xslo;
    *(uint4*)&ph[(size_t)r * XLD + 8 * o] = *(uint4*)h8;
    *(uint4*)&pl[(size_t)r * XLD + 8 * o] = *(uint4*)l8;
}

// ---------------------------------------------------------------------------
// Convert W [K][256] fp32 -> transposed hi/lo planes [256][Kpad].
// ---------------------------------------------------------------------------
__global__ void k_convW(const float* __restrict__ W, int K, int Kpad, int which) {
    int t = blockIdx.x * blockDim.x + threadIdx.x;
    if (t >= 256 * (Kpad / 8)) return;
    int c = t / (Kpad / 8), o = t - c * (Kpad / 8);
    unsigned short h8[8], l8[8];
#pragma unroll
    for (int j = 0; j < 8; j++) {
        int k = 8 * o + j;
        float x = (k < K) ? W[(size_t)k * 256 + c] : 0.f;
        unsigned short h = f2b(x);
        h8[j] = h;
        l8[j] = f2b(x - b2f(h));
    }
    *(uint4*)&wthi(which)[(size_t)c * Kpad + 8 * o] = *(uint4*)h8;
    *(uint4*)&wtlo(which)[(size_t)c * Kpad + 8 * o] = *(uint4*)l8;
}

// ---------------------------------------------------------------------------
// MFMA bf16x2-split GEMM from pre-converted planes (no VALU in staging).
// g_T[tbase+r][c] = X @ W. Tile 64x64, K-step 32, 4 waves.
// xsel: 0..3 = h/c planes (ld=kld), 4/5 = layer-1 x planes. x2sel>=0: cols 256+.
// ---------------------------------------------------------------------------
#define GK 32
#define ASTR 40
__global__ __launch_bounds__(256) void k_gemm_mfma(int xsel, int x2sel, int kld,
                                                   int K, int wsel, int wld,
                                                   int tbase) {
    __shared__ unsigned short Ah[64][ASTR], Al[64][ASTR];
    __shared__ unsigned short Bh[64][ASTR], Bl[64][ASTR];
    int tid = threadIdx.x;
    int id = blockIdx.x;
    int bn = id & 3, bm = id >> 2;
    int r0 = bm * 64, c0 = bn * 64;
    const unsigned short* whi_ = wthi(wsel);
    const unsigned short* wlo_ = wtlo(wsel);

    int w = tid >> 6;
    int l = tid & 63;
    int lr = l & 15;
    int lq = l >> 4;
    int koff = lq * 8;
    int sr = tid >> 2, so = (tid & 3) * 8;   // staging: row/col = sr, k-oct = so

    f32x4 acc[4];
#pragma unroll
    for (int c = 0; c < 4; c++) acc[c] = (f32x4){0.f, 0.f, 0.f, 0.f};

    int nt = K / GK;
    for (int t = 0; t < nt; t++) {
        int k0 = t * GK;
        const unsigned short *phi, *plo;
        int xc;
        if (x2sel >= 0 && k0 >= HID) { phi = selhi(x2sel); plo = sello(x2sel); xc = k0 - HID; }
        else                          { phi = selhi(xsel);  plo = sello(xsel);  xc = k0; }

        __syncthreads();
        {
            size_t ga = (size_t)(r0 + sr) * kld + xc + so;
            *(uint4*)&Ah[sr][so] = *(const uint4*)&phi[ga];
            *(uint4*)&Al[sr][so] = *(const uint4*)&plo[ga];
            size_t gb = (size_t)(c0 + sr) * wld + k0 + so;
            *(uint4*)&Bh[sr][so] = *(const uint4*)&whi_[gb];
            *(uint4*)&Bl[sr][so] = *(const uint4*)&wlo_[gb];
        }
        __syncthreads();

        bf16x8 ah = *(const bf16x8*)&Ah[16 * w + lr][koff];
        bf16x8 al = *(const bf16x8*)&Al[16 * w + lr][koff];
#pragma unroll
        for (int c = 0; c < 4; c++) {
            bf16x8 bh = *(const bf16x8*)&Bh[16 * c + lr][koff];
            bf16x8 bl = *(const bf16x8*)&Bl[16 * c + lr][koff];
            acc[c] = __builtin_amdgcn_mfma_f32_16x16x32_bf16(ah, bh, acc[c], 0, 0, 0);
            acc[c] = __builtin_amdgcn_mfma_f32_16x16x32_bf16(ah, bl, acc[c], 0, 0, 0);
            acc[c] = __builtin_amdgcn_mfma_f32_16x16x32_bf16(al, bh, acc[c], 0, 0, 0);
        }
    }

#pragma unroll
    for (int c = 0; c < 4; c++) {
#pragma unroll
        for (int qq = 0; qq < 4; qq++) {
            size_t row = (size_t)(tbase + r0 + 16 * w + 4 * lq + qq);
            g_T[row * HID + c0 + 16 * c + lr] = acc[c][qq];
        }
    }
}

// ---------------------------------------------------------------------------
// Fused two-stream aggregate; also emits bf16 hi/lo planes of h.
// ---------------------------------------------------------------------------
__global__ __launch_bounds__(256) void k_agg2(const float* __restrict__ bias,
                                              int hsel0, float* __restrict__ outS,
                                              float* __restrict__ outF) {
    __shared__ float AdjT[NODE][102];
    int tid = threadIdx.x;
    int idx = blockIdx.x;
    int side = idx >> 10;
    int b = (idx & 1023) >> 1;
    int c0 = (idx & 1) * 128;
    const float* Adj = adjPtr(side) + (size_t)b * NODE * NODE;
    const float* Tg = g_T + ((size_t)side * NN + (size_t)b * NODE) * HID;
    float* outp = side ? outF : outS;
    float* hdst = selbuf(hsel0 + side);
    unsigned short* phD = selhi(hsel0 + side);
    unsigned short* plD = sello(hsel0 + side);

    for (int i = tid; i < NODE * NODE; i += 256) {
        int n = i / NODE, k = i - n * NODE;
        AdjT[k][n] = Adj[i];
    }
    for (int i = tid; i < NODE * 12; i += 256) {
        int k = i / 12, n = NODE + (i % 12);
        AdjT[k][n] = 0.f;
    }
    __syncthreads();

    int ti = tid & 15, tj = tid >> 4;
    int rbase = 6 * ti;
    int cc = c0 + 8 * tj;

    float acc[6][8];
#pragma unroll
    for (int i = 0; i < 6; i++)
#pragma unroll
        for (int j = 0; j < 8; j++) acc[i][j] = 0.f;

#pragma unroll 2
    for (int k = 0; k < NODE; k++) {
        float4 t0 = *(const float4*)&Tg[(size_t)k * HID + cc];
        float4 t1 = *(const float4*)&Tg[(size_t)k * HID + cc + 4];
        float bv[8] = {t0.x, t0.y, t0.z, t0.w, t1.x, t1.y, t1.z, t1.w};
        float2 a01 = *(const float2*)&AdjT[k][rbase];
        float2 a23 = *(const float2*)&AdjT[k][rbase + 2];
        float2 a45 = *(const float2*)&AdjT[k][rbase + 4];
        float av[6] = {a01.x, a01.y, a23.x, a23.y, a45.x, a45.y};
#pragma unroll
        for (int i = 0; i < 6; i++)
#pragma unroll
            for (int j = 0; j < 8; j++)
                acc[i][j] = fmaf(av[i], bv[j], acc[i][j]);
    }

    float bb[8];
#pragma unroll
    for (int j = 0; j < 8; j++) bb[j] = bias[cc + j];

#pragma unroll
    for (int i = 0; i < 6; i++) {
        int n = rbase + i;
        if (n < NODE) {
            size_t row = (size_t)(b * NODE + n);
            float v[8];
            unsigned short h8[8], l8[8];
#pragma unroll
            for (int j = 0; j < 8; j++) {
                v[j] = fmaxf(acc[i][j] + bb[j], 0.f);
                unsigned short h = f2b(v[j]);
                h8[j] = h;
                l8[j] = f2b(v[j] - b2f(h));
            }
            float4 o0 = make_float4(v[0], v[1], v[2], v[3]);
            float4 o1 = make_float4(v[4], v[5], v[6], v[7]);
            *(float4*)&hdst[row * HID + cc] = o0;
            *(float4*)&hdst[row * HID + cc + 4] = o1;
            *(float4*)&outp[row * 512 + cc] = o0;
            *(float4*)&outp[row * 512 + cc + 4] = o1;
            *(uint4*)&phD[row * HID + cc] = *(uint4*)h8;
            *(uint4*)&plD[row * HID + cc] = *(uint4*)l8;
        }
    }
}

// ---------------------------------------------------------------------------
// Fused co-attention per graph; also emits bf16 hi/lo planes of cs/cf.
// ---------------------------------------------------------------------------
#define CO_THREADS 512
__global__ __launch_bounds__(CO_THREADS, 1) void k_coatt(int hfsel, int hssel,
                                                         float* __restrict__ outS,
                                                         float* __restrict__ outF,
                                                         int cssel, int cfsel) {
    __shared__ float hfl[NODE][258];
    __shared__ float Pm[NODE][92];
    __shared__ float t2s[NODE][34];
    __shared__ float rmax_[NODE], rinv_[NODE], fn_[NODE], gm_[NODE];

    int b = blockIdx.x;
    int tid = threadIdx.x;
    const float* HF = selbuf(hfsel) + (size_t)b * NODE * HID;
    const float* HS = selbuf(hssel) + (size_t)b * NODE * HID;
    const float* T2 = g_T + (size_t)b * NODE * HID;

    for (int i = tid; i < NODE * 64; i += CO_THREADS) {
        int n = i >> 6, c4 = (i & 63) << 2;
        *(float4*)&hfl[n][c4] = *(const float4*)&HF[(size_t)n * HID + c4];
    }

    {
        const int tm = tid & 31;
        const int tn5 = tid >> 5;
        const float* hr0 = hfl[tm];
        const float* hr1 = hfl[tm + 32];
        const float* hr2 = hfl[(tm < 26) ? tm + 64 : 0];
        const float* tr[6];
#pragma unroll
        for (int k = 0; k < 6; k++) {
            int n = tn5 + 16 * k;
            tr[k] = t2s[(n < NODE) ? n : 0];
        }
        float at[3][6];
#pragma unroll
        for (int i = 0; i < 3; i++)
#pragma unroll
            for (int k = 0; k < 6; k++) at[i][k] = 0.f;

        for (int d0 = 0; d0 < HID; d0 += 32) {
            __syncthreads();
            for (int i = tid; i < NODE * 32; i += CO_THREADS) {
                int n = i >> 5, dd = i & 31;
                t2s[n][dd] = T2[(size_t)n * HID + d0 + dd];
            }
            __syncthreads();
#pragma unroll
            for (int dd = 0; dd < 32; dd += 2) {
                float2 a0 = *(const float2*)&hr0[d0 + dd];
                float2 a1 = *(const float2*)&hr1[d0 + dd];
                float2 a2 = *(const float2*)&hr2[d0 + dd];
#pragma unroll
                for (int k = 0; k < 6; k++) {
                    float2 bk = *(const float2*)&tr[k][dd];
                    at[0][k] = fmaf(a0.x, bk.x, at[0][k]);
                    at[0][k] = fmaf(a0.y, bk.y, at[0][k]);
                    at[1][k] = fmaf(a1.x, bk.x, at[1][k]);
                    at[1][k] = fmaf(a1.y, bk.y, at[1][k]);
                    at[2][k] = fmaf(a2.x, bk.x, at[2][k]);
                    at[2][k] = fmaf(a2.y, bk.y, at[2][k]);
                }
            }
        }
        __syncthreads();
        int mv[3] = {tm, tm + 32, tm + 64};
#pragma unroll
        for (int i = 0; i < 3; i++) {
            if (mv[i] < NODE) {
#pragma unroll
                for (int k = 0; k < 6; k++) {
                    int n = tn5 + 16 * k;
                    if (n < NODE) Pm[n][mv[i]] = tanh_safe(at[i][k]);
                }
            }
        }
    }
    __syncthreads();

    if (tid < NODE) {
        int n = tid;
        float mx = -2.f;
        for (int m = 0; m < NODE; m++) mx = fmaxf(mx, Pm[n][m]);
        float s = 0.f;
        for (int m = 0; m < NODE; m++) s += __expf(Pm[n][m] - mx);
        rmax_[n] = mx;
        rinv_[n] = 1.f / s;
        fn_[n] = s * __expf(mx);
    } else if (tid >= 256 && tid < 256 + NODE) {
        int m = tid - 256;
        float mx = -2.f;
        for (int n = 0; n < NODE; n++) mx = fmaxf(mx, Pm[n][m]);
        float s = 0.f;
        for (int n = 0; n < NODE; n++) s += __expf(Pm[n][m] - mx);
        gm_[m] = __expf(-mx) / s;
    }
    __syncthreads();

    for (int i = tid; i < NODE * NODE; i += CO_THREADS) {
        int n = i / NODE, m = i - n * NODE;
        Pm[n][m] = __expf(Pm[n][m] - rmax_[n]) * rinv_[n];
    }
    __syncthreads();

    {
        const int tc4 = (tid & 63) << 2;
        const int tnn = tid >> 6;
        int nrow[12];
#pragma unroll
        for (int k = 0; k < 12; k++) {
            int n = tnn + 8 * k;
            nrow[k] = (n < NODE) ? n : 0;
        }
        float acc[12][4];
#pragma unroll
        for (int k = 0; k < 12; k++)
#pragma unroll
            for (int j = 0; j < 4; j++) acc[k][j] = 0.f;

#pragma unroll 2
        for (int m = 0; m < NODE; m++) {
            float4 h = *(const float4*)&hfl[m][tc4];
#pragma unroll
            for (int k = 0; k < 12; k++) {
                float p = Pm[nrow[k]][m];
                acc[k][0] = fmaf(p, h.x, acc[k][0]);
                acc[k][1] = fmaf(p, h.y, acc[k][1]);
                acc[k][2] = fmaf(p, h.z, acc[k][2]);
                acc[k][3] = fmaf(p, h.w, acc[k][3]);
            }
        }
        float* cs = selbuf(cssel);
        unsigned short* csh = selhi(cssel);
        unsigned short* csl = sello(cssel);
#pragma unroll
        for (int k = 0; k < 12; k++) {
            int n = tnn + 8 * k;
            if (n < NODE) {
                size_t row = (size_t)(b * NODE + n);
                float4 o = make_float4(acc[k][0], acc[k][1], acc[k][2], acc[k][3]);
                *(float4*)&outS[row * 512 + tc4] = o;
                *(float4*)&cs[row * HID + tc4] = o;
                unsigned short h4[4], l4[4];
#pragma unroll
                for (int j = 0; j < 4; j++) {
                    unsigned short h = f2b(acc[k][j]);
                    h4[j] = h;
                    l4[j] = f2b(acc[k][j] - b2f(h));
                }
                *(uint2*)&csh[row * HID + tc4] = *(uint2*)h4;
                *(uint2*)&csl[row * HID + tc4] = *(uint2*)l4;
            }
        }
    }
    __syncthreads();

    for (int i = tid; i < NODE * 64; i += CO_THREADS) {
        int n = i >> 6, c4 = (i & 63) << 2;
        *(float4*)&hfl[n][c4] = *(const float4*)&HS[(size_t)n * HID + c4];
    }
    for (int i = tid; i < NODE * NODE; i += CO_THREADS) {
        int n = i / NODE, m = i - n * NODE;
        Pm[n][m] *= fn_[n];
    }
    __syncthreads();

    {
        const int tc4 = (tid & 63) << 2;
        const int tmm = tid >> 6;
        int mrow[12];
#pragma unroll
        for (int k = 0; k < 12; k++) {
            int m = tmm + 8 * k;
            mrow[k] = (m < NODE) ? m : 0;
        }
        float acc[12][4];
#pragma unroll
        for (int k = 0; k < 12; k++)
#pragma unroll
            for (int j = 0; j < 4; j++) acc[k][j] = 0.f;

#pragma unroll 2
        for (int n = 0; n < NODE; n++) {
            float4 h = *(const float4*)&hfl[n][tc4];
#pragma unroll
            for (int k = 0; k < 12; k++) {
                float p = Pm[n][mrow[k]];
                acc[k][0] = fmaf(p, h.x, acc[k][0]);
                acc[k][1] = fmaf(p, h.y, acc[k][1]);
                acc[k][2] = fmaf(p, h.z, acc[k][2]);
                acc[k][3] = fmaf(p, h.w, acc[k][3]);
            }
        }
        float* cf = selbuf(cfsel);
        unsigned short* cfh = selhi(cfsel);
        unsigned short* cfl = sello(cfsel);
#pragma unroll
        for (int k = 0; k < 12; k++) {
            int m = tmm + 8 * k;
            if (m < NODE) {
                float g = gm_[m];
                size_t row = (size_t)(b * NODE + m);
                float o4[4] = {acc[k][0] * g, acc[k][1] * g, acc[k][2] * g, acc[k][3] * g};
                *(float4*)&outF[row * 512 + tc4] = make_float4(o4[0], o4[1], o4[2], o4[3]);
                *(float4*)&cf[row * HID + tc4] = make_float4(o4[0], o4[1], o4[2], o4[3]);
                unsigned short h4[4], l4[4];
#pragma unroll
                for (int j = 0; j < 4; j++) {
                    unsigned short h = f2b(o4[j]);
                    h4[j] = h;
                    l4[j] = f2b(o4[j] - b2f(h));
                }
                *(uint2*)&cfh[row * HID + tc4] = *(uint2*)h4;
                *(uint2*)&cfl[row * HID + tc4] = *(uint2*)l4;
            }
        }
    }
}

// ---------------------------------------------------------------------------
extern "C" void kernel_launch(void* const* d_in, const int* in_sizes, int n_in,
                              void* d_out, int out_size, void* d_ws, size_t ws_size,
                              hipStream_t stream) {
    const float* x_sc = (const float*)d_in[0];
    const void* e_sc = d_in[1];
    const float* x_fc = (const float*)d_in[2];
    const void* e_fc = d_in[3];
    const float* W0 = (const float*)d_in[4];
    const float* b0 = (const float*)d_in[5];
    const float* W1 = (const float*)d_in[6];
    const float* b1 = (const float*)d_in[7];
    const float* Wa = (const float*)d_in[8];

    float* out = (float*)d_out;
    size_t os = (size_t)NN * 512;
    float* x1s = out;
    float* x2s = out + os;
    float* x1f = out + 2 * os;
    float* x2f = out + 3 * os;

    const int GG = (NN / 64) * 4;   // 2880 blocks per GEMM dispatch

    k_detect<<<1, 64, 0, stream>>>(e_sc);
    k_adj_fused<<<1024, 256, 0, stream>>>(e_sc, e_fc);

    // conversions (weights tiny; X ~70 MB traffic)
    k_convW<<<(256 * (XLD / 8) + 255) / 256, 256, 0, stream>>>(W0, NODE, XLD, 0);
    k_convW<<<(256 * 32 + 255) / 256, 256, 0, stream>>>(Wa, HID, 256, 1);
    k_convW<<<(256 * 64 + 255) / 256, 256, 0, stream>>>(W1, 512, 512, 2);
    k_convX<<<(NN * (XLD / 8) + 255) / 256, 256, 0, stream>>>(x_sc, 0);
    k_convX<<<(NN * (XLD / 8) + 255) / 256, 256, 0, stream>>>(x_fc, 1);

    // ---- layer 1: T_S = x_sc @ W0, T_F = x_fc @ W0 (Kpad=96) ----
    k_gemm_mfma<<<GG, 256, 0, stream>>>(4, -1, XLD, XLD, 0, XLD, 0);
    k_gemm_mfma<<<GG, 256, 0, stream>>>(5, -1, XLD, XLD, 0, XLD, NN);
    k_agg2<<<2048, 256, 0, stream>>>(b0, /*hs/hf*/0, x1s, x1f);

    // ---- co-attention 1: T2 = hs @ Wa (K=256) ----
    k_gemm_mfma<<<GG, 256, 0, stream>>>(0, -1, HID, 256, 1, 256, 0);
    k_coatt<<<NB, CO_THREADS, 0, stream>>>(/*hf*/1, /*hs*/0, x1s + HID, x1f + HID, 2, 3);

    // ---- layer 2: T = [h|c] @ W1 (K=512) ----
    k_gemm_mfma<<<GG, 256, 0, stream>>>(0, 2, HID, 512, 2, 512, 0);
    k_gemm_mfma<<<GG, 256, 0, stream>>>(1, 3, HID, 512, 2, 512, NN);
    k_agg2<<<2048, 256, 0, stream>>>(b1, /*hs2/hf2*/0, x2s, x2f);

    // ---- co-attention 2 ----
    k_gemm_mfma<<<GG, 256, 0, stream>>>(0, -1, HID, 256, 1, 256, 0);
    k_coatt<<<NB, CO_THREADS, 0, stream>>>(/*hf2*/1, /*hs2*/0, x2s + HID, x2f + HID, 2, 3);
}

// Round 15
// 1202.650 us; speedup vs baseline: 1.2729x; 1.0033x over previous
//
#include <hip/hip_runtime.h>
#include <hip/hip_bf16.h>
#include <math.h>

#define NODE 90
#define HID 256
#define NB 512
#define NN (NB * NODE)
#define EDGES (NB * 2700)
#define XLD 96

typedef __attribute__((ext_vector_type(8))) short bf16x8;
typedef __attribute__((ext_vector_type(4))) float f32x4;

__device__ __forceinline__ float tanh_safe(float s) {
    s = fminf(fmaxf(s, -15.f), 15.f);
    float t = __expf(2.f * s);
    return (t - 1.f) / (t + 1.f);
}
__device__ __forceinline__ unsigned short f2b(float x) {
    unsigned u = __float_as_uint(x);
    return (unsigned short)((u + 0x7FFFu + ((u >> 16) & 1u)) >> 16);
}
__device__ __forceinline__ float b2f(unsigned short h) {
    return __uint_as_float(((unsigned)h) << 16);
}

// ---------------------------------------------------------------------------
__device__ float g_adjS[(size_t)NB * NODE * NODE];
__device__ float g_adjF[(size_t)NB * NODE * NODE];
__device__ float g_T[(size_t)2 * NN * HID];
__device__ float g_hs[(size_t)NN * HID];
__device__ float g_hf[(size_t)NN * HID];
__device__ float g_P[(size_t)NB * NODE * NODE];
__device__ float g_fn[NB * 96];
__device__ float g_gm[NB * 96];
__device__ int g_flags[2];

__device__ unsigned short g_hshi[(size_t)NN * HID], g_hslo[(size_t)NN * HID];
__device__ unsigned short g_hfhi[(size_t)NN * HID], g_hflo[(size_t)NN * HID];
__device__ unsigned short g_cshi[(size_t)NN * HID], g_cslo[(size_t)NN * HID];
__device__ unsigned short g_cfhi[(size_t)NN * HID], g_cflo[(size_t)NN * HID];
__device__ unsigned short g_xshi[(size_t)NN * XLD], g_xslo[(size_t)NN * XLD];
__device__ unsigned short g_xfhi[(size_t)NN * XLD], g_xflo[(size_t)NN * XLD];
__device__ unsigned short g_w0thi[256 * XLD], g_w0tlo[256 * XLD];
__device__ unsigned short g_wathi[256 * 256], g_watlo[256 * 256];
__device__ unsigned short g_w1thi[256 * 512], g_w1tlo[256 * 512];

__device__ __forceinline__ float* adjPtr(int w) { return w ? g_adjF : g_adjS; }
__device__ __forceinline__ float* selbuf(int w) { return w ? g_hf : g_hs; }
__device__ __forceinline__ unsigned short* selhi(int w) {
    switch (w) {
        case 0: return g_hshi;
        case 1: return g_hfhi;
        case 2: return g_cshi;
        case 3: return g_cfhi;
        case 4: return g_xshi;
        default: return g_xfhi;
    }
}
__device__ __forceinline__ unsigned short* sello(int w) {
    switch (w) {
        case 0: return g_hslo;
        case 1: return g_hflo;
        case 2: return g_cslo;
        case 3: return g_cflo;
        case 4: return g_xslo;
        default: return g_xflo;
    }
}
__device__ __forceinline__ unsigned short* wthi(int w) {
    switch (w) { case 0: return g_w0thi; case 1: return g_wathi; default: return g_w1thi; }
}
__device__ __forceinline__ unsigned short* wtlo(int w) {
    switch (w) { case 0: return g_w0tlo; case 1: return g_watlo; default: return g_w1tlo; }
}

// ---------------------------------------------------------------------------
__global__ void k_detect(const void* edges) {
    if (threadIdx.x != 0 || blockIdx.x != 0) return;
    const int* ei = (const int*)edges;
    int odd_nonzero = 0;
    for (int i = 0; i < 2048; i += 2)
        if (ei[i + 1] != 0) odd_nonzero = 1;
    g_flags[1] = odd_nonzero ? 0 : 1;
}

// ---------------------------------------------------------------------------
__global__ __launch_bounds__(256) void k_adj_fused(const void* __restrict__ eS,
                                                   const void* __restrict__ eF) {
    __shared__ float cnt[NODE][NODE + 1];
    __shared__ float dinv[NODE];
    int side = blockIdx.x >> 9;
    int b = blockIdx.x & 511;
    const void* edges = side ? eF : eS;
    int tid = threadIdx.x;
    for (int i = tid; i < NODE * (NODE + 1); i += 256) (&cnt[0][0])[i] = 0.f;
    __syncthreads();
    int e64 = g_flags[1];
    const long long* p64 = (const long long*)edges;
    const int* p32 = (const int*)edges;
    for (int i = tid; i < 2700; i += 256) {
        int idx = b * 2700 + i;
        long long s, d;
        if (e64) { s = p64[idx]; d = p64[EDGES + idx]; }
        else     { s = p32[idx]; d = p32[EDGES + idx]; }
        int sl = (int)s - b * NODE, dl = (int)d - b * NODE;
        if (sl >= 0 && sl < NODE && dl >= 0 && dl < NODE)
            atomicAdd(&cnt[dl][sl], 1.0f);
    }
    __syncthreads();
    if (tid < NODE) {
        float s = 0.f;
        for (int k = 0; k < NODE; k++) s += cnt[tid][k];
        dinv[tid] = (s > 0.f) ? rsqrtf(s) : 0.f;
    }
    __syncthreads();
    float* adj = adjPtr(side) + (size_t)b * NODE * NODE;
    for (int i = tid; i < NODE * NODE; i += 256) {
        int d = i / NODE, s = i - d * NODE;
        adj[i] = cnt[d][s] * dinv[d] * dinv[s];
    }
}

// ---------------------------------------------------------------------------
__global__ void k_convX(const float* __restrict__ X, int side) {
    int t = blockIdx.x * blockDim.x + threadIdx.x;
    if (t >= NN * (XLD / 8)) return;
    int r = t / (XLD / 8), o = t - r * (XLD / 8);
    unsigned short h8[8], l8[8];
#pragma unroll
    for (int j = 0; j < 8; j++) {
        int k = 8 * o + j;
        float x = (k < NODE) ? X[(size_t)r * NODE + k] : 0.f;
        unsigned short h = f2b(x);
        h8[j] = h;
        l8[j] = f2b(x - b2f(h));
    }
    unsigned short* ph = side ? g_xfhi : g_xshi;
    unsigned short* pl = side ? g_xflo : g_xslo;
    *(uint4*)&ph[(size_t)r * XLD + 8 * o] = *(uint4*)h8;
    *(uint4*)&pl[(size_t)r * XLD + 8 * o] = *(uint4*)l8;
}

__global__ void k_convW(const float* __restrict__ W, int K, int Kpad, int which) {
    int t = blockIdx.x * blockDim.x + threadIdx.x;
    if (t >= 256 * (Kpad / 8)) return;
    int c = t / (Kpad / 8), o = t - c * (Kpad / 8);
    unsigned short h8[8], l8[8];
#pragma unroll
    for (int j = 0; j < 8; j++) {
        int k = 8 * o + j;
        float x = (k < K) ? W[(size_t)k * 256 + c] : 0.f;
        unsigned short h = f2b(x);
        h8[j] = h;
        l8[j] = f2b(x - b2f(h));
    }
    *(uint4*)&wthi(which)[(size_t)c * Kpad + 8 * o] = *(uint4*)h8;
    *(uint4*)&wtlo(which)[(size_t)c * Kpad + 8 * o] = *(uint4*)l8;
}

// ---------------------------------------------------------------------------
// MFMA bf16x2-split GEMM from planes -> fp32 g_T. (validated r12/r13)
// ---------------------------------------------------------------------------
#define GK 32
#define ASTR 40
__global__ __launch_bounds__(256) void k_gemm_mfma(int xsel, int x2sel, int kld,
                                                   int K, int wsel, int wld,
                                                   int tbase) {
    __shared__ unsigned short Ah[64][ASTR], Al[64][ASTR];
    __shared__ unsigned short Bh[64][ASTR], Bl[64][ASTR];
    int tid = threadIdx.x;
    int id = blockIdx.x;
    int bn = id & 3, bm = id >> 2;
    int r0 = bm * 64, c0 = bn * 64;
    const unsigned short* whi_ = wthi(wsel);
    const unsigned short* wlo_ = wtlo(wsel);

    int w = tid >> 6;
    int l = tid & 63;
    int lr = l & 15;
    int lq = l >> 4;
    int koff = lq * 8;
    int sr = tid >> 2, so = (tid & 3) * 8;

    f32x4 acc[4];
#pragma unroll
    for (int c = 0; c < 4; c++) acc[c] = (f32x4){0.f, 0.f, 0.f, 0.f};

    int nt = K / GK;
    for (int t = 0; t < nt; t++) {
        int k0 = t * GK;
        const unsigned short *phi, *plo;
        int xc;
        if (x2sel >= 0 && k0 >= HID) { phi = selhi(x2sel); plo = sello(x2sel); xc = k0 - HID; }
        else                          { phi = selhi(xsel);  plo = sello(xsel);  xc = k0; }

        __syncthreads();
        {
            size_t ga = (size_t)(r0 + sr) * kld + xc + so;
            *(uint4*)&Ah[sr][so] = *(const uint4*)&phi[ga];
            *(uint4*)&Al[sr][so] = *(const uint4*)&plo[ga];
            size_t gb = (size_t)(c0 + sr) * wld + k0 + so;
            *(uint4*)&Bh[sr][so] = *(const uint4*)&whi_[gb];
            *(uint4*)&Bl[sr][so] = *(const uint4*)&wlo_[gb];
        }
        __syncthreads();

        bf16x8 ah = *(const bf16x8*)&Ah[16 * w + lr][koff];
        bf16x8 al = *(const bf16x8*)&Al[16 * w + lr][koff];
#pragma unroll
        for (int c = 0; c < 4; c++) {
            bf16x8 bh = *(const bf16x8*)&Bh[16 * c + lr][koff];
            bf16x8 bl = *(const bf16x8*)&Bl[16 * c + lr][koff];
            acc[c] = __builtin_amdgcn_mfma_f32_16x16x32_bf16(ah, bh, acc[c], 0, 0, 0);
            acc[c] = __builtin_amdgcn_mfma_f32_16x16x32_bf16(ah, bl, acc[c], 0, 0, 0);
            acc[c] = __builtin_amdgcn_mfma_f32_16x16x32_bf16(al, bh, acc[c], 0, 0, 0);
        }
    }

#pragma unroll
    for (int c = 0; c < 4; c++) {
#pragma unroll
        for (int qq = 0; qq < 4; qq++) {
            size_t row = (size_t)(tbase + r0 + 16 * w + 4 * lq + qq);
            g_T[row * HID + c0 + 16 * c + lr] = acc[c][qq];
        }
    }
}

// ---------------------------------------------------------------------------
// Fused two-stream aggregate; emits h fp32 + hi/lo planes. (validated)
// ---------------------------------------------------------------------------
__global__ __launch_bounds__(256) void k_agg2(const float* __restrict__ bias,
                                              float* __restrict__ outS,
                                              float* __restrict__ outF) {
    __shared__ float AdjT[NODE][102];
    int tid = threadIdx.x;
    int idx = blockIdx.x;
    int side = idx >> 10;
    int b = (idx & 1023) >> 1;
    int c0 = (idx & 1) * 128;
    const float* Adj = adjPtr(side) + (size_t)b * NODE * NODE;
    const float* Tg = g_T + ((size_t)side * NN + (size_t)b * NODE) * HID;
    float* outp = side ? outF : outS;
    float* hdst = selbuf(side);
    unsigned short* phD = selhi(side);
    unsigned short* plD = sello(side);

    for (int i = tid; i < NODE * NODE; i += 256) {
        int n = i / NODE, k = i - n * NODE;
        AdjT[k][n] = Adj[i];
    }
    for (int i = tid; i < NODE * 12; i += 256) {
        int k = i / 12, n = NODE + (i % 12);
        AdjT[k][n] = 0.f;
    }
    __syncthreads();

    int ti = tid & 15, tj = tid >> 4;
    int rbase = 6 * ti;
    int cc = c0 + 8 * tj;

    float acc[6][8];
#pragma unroll
    for (int i = 0; i < 6; i++)
#pragma unroll
        for (int j = 0; j < 8; j++) acc[i][j] = 0.f;

#pragma unroll 2
    for (int k = 0; k < NODE; k++) {
        float4 t0 = *(const float4*)&Tg[(size_t)k * HID + cc];
        float4 t1 = *(const float4*)&Tg[(size_t)k * HID + cc + 4];
        float bv[8] = {t0.x, t0.y, t0.z, t0.w, t1.x, t1.y, t1.z, t1.w};
        float2 a01 = *(const float2*)&AdjT[k][rbase];
        float2 a23 = *(const float2*)&AdjT[k][rbase + 2];
        float2 a45 = *(const float2*)&AdjT[k][rbase + 4];
        float av[6] = {a01.x, a01.y, a23.x, a23.y, a45.x, a45.y};
#pragma unroll
        for (int i = 0; i < 6; i++)
#pragma unroll
            for (int j = 0; j < 8; j++)
                acc[i][j] = fmaf(av[i], bv[j], acc[i][j]);
    }

    float bb[8];
#pragma unroll
    for (int j = 0; j < 8; j++) bb[j] = bias[cc + j];

#pragma unroll
    for (int i = 0; i < 6; i++) {
        int n = rbase + i;
        if (n < NODE) {
            size_t row = (size_t)(b * NODE + n);
            float v[8];
            unsigned short h8[8], l8[8];
#pragma unroll
            for (int j = 0; j < 8; j++) {
                v[j] = fmaxf(acc[i][j] + bb[j], 0.f);
                unsigned short h = f2b(v[j]);
                h8[j] = h;
                l8[j] = f2b(v[j] - b2f(h));
            }
            float4 o0 = make_float4(v[0], v[1], v[2], v[3]);
            float4 o1 = make_float4(v[4], v[5], v[6], v[7]);
            *(float4*)&hdst[row * HID + cc] = o0;
            *(float4*)&hdst[row * HID + cc + 4] = o1;
            *(float4*)&outp[row * 512 + cc] = o0;
            *(float4*)&outp[row * 512 + cc + 4] = o1;
            *(uint4*)&phD[row * HID + cc] = *(uint4*)h8;
            *(uint4*)&plD[row * HID + cc] = *(uint4*)l8;
        }
    }
}

// ---------------------------------------------------------------------------
// fp32 scores per graph (r13-validated phase-1 + stats):
//   At[n][m] = tanh(dot(g_T[b,n,:], HF[b,m,:]))
//   stats -> rmax/rinv/fn/gm; P = row-softmax(At) -> g_P; fn/gm -> global.
// ---------------------------------------------------------------------------
#define CO_THREADS 512
__global__ __launch_bounds__(CO_THREADS, 1) void k_score_f32(int hfsel) {
    __shared__ float hfl[NODE][258];
    __shared__ float Pm[NODE][92];
    __shared__ float t2s[NODE][34];
    __shared__ float rmax_[NODE], rinv_[NODE], fn_[NODE], gm_[NODE];

    int b = blockIdx.x;
    int tid = threadIdx.x;
    const float* HF = selbuf(hfsel) + (size_t)b * NODE * HID;
    const float* T2 = g_T + (size_t)b * NODE * HID;

    for (int i = tid; i < NODE * 64; i += CO_THREADS) {
        int n = i >> 6, c4 = (i & 63) << 2;
        *(float4*)&hfl[n][c4] = *(const float4*)&HF[(size_t)n * HID + c4];
    }

    {
        const int tm = tid & 31;
        const int tn5 = tid >> 5;
        const float* hr0 = hfl[tm];
        const float* hr1 = hfl[tm + 32];
        const float* hr2 = hfl[(tm < 26) ? tm + 64 : 0];
        const float* tr[6];
#pragma unroll
        for (int k = 0; k < 6; k++) {
            int n = tn5 + 16 * k;
            tr[k] = t2s[(n < NODE) ? n : 0];
        }
        float at[3][6];
#pragma unroll
        for (int i = 0; i < 3; i++)
#pragma unroll
            for (int k = 0; k < 6; k++) at[i][k] = 0.f;

        for (int d0 = 0; d0 < HID; d0 += 32) {
            __syncthreads();
            for (int i = tid; i < NODE * 32; i += CO_THREADS) {
                int n = i >> 5, dd = i & 31;
                t2s[n][dd] = T2[(size_t)n * HID + d0 + dd];
            }
            __syncthreads();
#pragma unroll
            for (int dd = 0; dd < 32; dd += 2) {
                float2 a0 = *(const float2*)&hr0[d0 + dd];
                float2 a1 = *(const float2*)&hr1[d0 + dd];
                float2 a2 = *(const float2*)&hr2[d0 + dd];
#pragma unroll
                for (int k = 0; k < 6; k++) {
                    float2 bk = *(const float2*)&tr[k][dd];
                    at[0][k] = fmaf(a0.x, bk.x, at[0][k]);
                    at[0][k] = fmaf(a0.y, bk.y, at[0][k]);
                    at[1][k] = fmaf(a1.x, bk.x, at[1][k]);
                    at[1][k] = fmaf(a1.y, bk.y, at[1][k]);
                    at[2][k] = fmaf(a2.x, bk.x, at[2][k]);
                    at[2][k] = fmaf(a2.y, bk.y, at[2][k]);
                }
            }
        }
        __syncthreads();
        int mv[3] = {tm, tm + 32, tm + 64};
#pragma unroll
        for (int i = 0; i < 3; i++) {
            if (mv[i] < NODE) {
#pragma unroll
                for (int k = 0; k < 6; k++) {
                    int n = tn5 + 16 * k;
                    if (n < NODE) Pm[n][mv[i]] = tanh_safe(at[i][k]);
                }
            }
        }
    }
    __syncthreads();

    if (tid < NODE) {
        int n = tid;
        float mx = -2.f;
        for (int m = 0; m < NODE; m++) mx = fmaxf(mx, Pm[n][m]);
        float s = 0.f;
        for (int m = 0; m < NODE; m++) s += __expf(Pm[n][m] - mx);
        rmax_[n] = mx;
        rinv_[n] = 1.f / s;
        fn_[n] = s * __expf(mx);
    } else if (tid >= 256 && tid < 256 + NODE) {
        int m = tid - 256;
        float mx = -2.f;
        for (int n = 0; n < NODE; n++) mx = fmaxf(mx, Pm[n][m]);
        float s = 0.f;
        for (int n = 0; n < NODE; n++) s += __expf(Pm[n][m] - mx);
        gm_[m] = __expf(-mx) / s;
    }
    __syncthreads();

    float* Pg = g_P + (size_t)b * NODE * NODE;
    for (int i = tid; i < NODE * NODE; i += CO_THREADS) {
        int n = i / NODE, m = i - n * NODE;
        Pg[i] = __expf(Pm[n][m] - rmax_[n]) * rinv_[n];
    }
    if (tid < NODE) {
        g_fn[b * 96 + tid] = fn_[tid];
        g_gm[b * 96 + tid] = gm_[tid];
    }
}

// ---------------------------------------------------------------------------
// co_s = P @ HF (half-width panel per block). grid = NB*2.
// ---------------------------------------------------------------------------
__global__ __launch_bounds__(256) void k_pv2(int fsel, int cssel,
                                             float* __restrict__ outp, int emit) {
    __shared__ float Pl[NODE][91];
    __shared__ float Hl[NODE][129];
    int b = blockIdx.x >> 1;
    int c0 = (blockIdx.x & 1) * 128;
    int tid = threadIdx.x;
    const float* Pg = g_P + (size_t)b * NODE * NODE;
    for (int i = tid; i < NODE * NODE; i += 256) {
        int n = i / NODE, m = i - n * NODE;
        Pl[n][m] = Pg[i];
    }
    const float* H = selbuf(fsel) + (size_t)b * NODE * HID;
    for (int i = tid; i < NODE * 32; i += 256) {
        int r = i >> 5, c4 = (i & 31) << 2;
        *(float4*)&Hl[r][c4] = *(const float4*)&H[(size_t)r * HID + c0 + c4];
    }
    __syncthreads();

    int c4 = (tid & 31) << 2;
    int rg = tid >> 5;
    float acc[12][4];
#pragma unroll
    for (int k = 0; k < 12; k++)
#pragma unroll
        for (int j = 0; j < 4; j++) acc[k][j] = 0.f;

#pragma unroll 2
    for (int m = 0; m < NODE; m++) {
        float4 h = *(const float4*)&Hl[m][c4];
#pragma unroll
        for (int k = 0; k < 12; k++) {
            int n = rg + 8 * k;
            float p = Pl[(n < NODE) ? n : 0][m];
            acc[k][0] = fmaf(p, h.x, acc[k][0]);
            acc[k][1] = fmaf(p, h.y, acc[k][1]);
            acc[k][2] = fmaf(p, h.z, acc[k][2]);
            acc[k][3] = fmaf(p, h.w, acc[k][3]);
        }
    }

    unsigned short* csh = selhi(cssel);
    unsigned short* csl = sello(cssel);
#pragma unroll
    for (int k = 0; k < 12; k++) {
        int n = rg + 8 * k;
        if (n < NODE) {
            size_t row = (size_t)(b * NODE + n);
            size_t gc = c0 + c4;
            *(float4*)&outp[row * 512 + gc] =
                make_float4(acc[k][0], acc[k][1], acc[k][2], acc[k][3]);
            if (emit) {
                unsigned short h4[4], l4[4];
#pragma unroll
                for (int j = 0; j < 4; j++) {
                    unsigned short h = f2b(acc[k][j]);
                    h4[j] = h;
                    l4[j] = f2b(acc[k][j] - b2f(h));
                }
                *(uint2*)&csh[row * HID + gc] = *(uint2*)h4;
                *(uint2*)&csl[row * HID + gc] = *(uint2*)l4;
            }
        }
    }
}

// ---------------------------------------------------------------------------
// co_f[m] = gm[m] * Σ_n (P[n][m]*fn[n]) * HS[n]. grid = NB*2.
// ---------------------------------------------------------------------------
__global__ __launch_bounds__(256) void k_pv3(int ssel, int cfsel,
                                             float* __restrict__ outp, int emit) {
    __shared__ float Pl[NODE][91];
    __shared__ float Hl[NODE][129];
    __shared__ float fnl[96], gml[96];
    int b = blockIdx.x >> 1;
    int c0 = (blockIdx.x & 1) * 128;
    int tid = threadIdx.x;
    const float* Pg = g_P + (size_t)b * NODE * NODE;
    for (int i = tid; i < NODE * NODE; i += 256) {
        int n = i / NODE, m = i - n * NODE;
        Pl[n][m] = Pg[i];
    }
    const float* H = selbuf(ssel) + (size_t)b * NODE * HID;
    for (int i = tid; i < NODE * 32; i += 256) {
        int r = i >> 5, c4 = (i & 31) << 2;
        *(float4*)&Hl[r][c4] = *(const float4*)&H[(size_t)r * HID + c0 + c4];
    }
    if (tid < 96) {
        fnl[tid] = (tid < NODE) ? g_fn[b * 96 + tid] : 0.f;
        gml[tid] = (tid < NODE) ? g_gm[b * 96 + tid] : 0.f;
    }
    __syncthreads();

    int c4 = (tid & 31) << 2;
    int rg = tid >> 5;
    float acc[12][4];
#pragma unroll
    for (int k = 0; k < 12; k++)
#pragma unroll
        for (int j = 0; j < 4; j++) acc[k][j] = 0.f;

#pragma unroll 2
    for (int n = 0; n < NODE; n++) {
        float4 h = *(const float4*)&Hl[n][c4];
        float f = fnl[n];
#pragma unroll
        for (int k = 0; k < 12; k++) {
            int m = rg + 8 * k;
            float p = Pl[n][(m < NODE) ? m : 0] * f;
            acc[k][0] = fmaf(p, h.x, acc[k][0]);
            acc[k][1] = fmaf(p, h.y, acc[k][1]);
            acc[k][2] = fmaf(p, h.z, acc[k][2]);
            acc[k][3] = fmaf(p, h.w, acc[k][3]);
        }
    }

    unsigned short* cfh = selhi(cfsel);
    unsigned short* cfl = sello(cfsel);
#pragma unroll
    for (int k = 0; k < 12; k++) {
        int m = rg + 8 * k;
        if (m < NODE) {
            float g = gml[m];
            size_t row = (size_t)(b * NODE + m);
            size_t gc = c0 + c4;
            float o4[4] = {acc[k][0] * g, acc[k][1] * g, acc[k][2] * g, acc[k][3] * g};
            *(float4*)&outp[row * 512 + gc] = make_float4(o4[0], o4[1], o4[2], o4[3]);
            if (emit) {
                unsigned short h4[4], l4[4];
#pragma unroll
                for (int j = 0; j < 4; j++) {
                    unsigned short h = f2b(o4[j]);
                    h4[j] = h;
                    l4[j] = f2b(o4[j] - b2f(h));
                }
                *(uint2*)&cfh[row * HID + gc] = *(uint2*)h4;
                *(uint2*)&cfl[row * HID + gc] = *(uint2*)l4;
            }
        }
    }
}

// ---------------------------------------------------------------------------
extern "C" void kernel_launch(void* const* d_in, const int* in_sizes, int n_in,
                              void* d_out, int out_size, void* d_ws, size_t ws_size,
                              hipStream_t stream) {
    const float* x_sc = (const float*)d_in[0];
    const void* e_sc = d_in[1];
    const float* x_fc = (const float*)d_in[2];
    const void* e_fc = d_in[3];
    const float* W0 = (const float*)d_in[4];
    const float* b0 = (const float*)d_in[5];
    const float* W1 = (const float*)d_in[6];
    const float* b1 = (const float*)d_in[7];
    const float* Wa = (const float*)d_in[8];

    float* out = (float*)d_out;
    size_t os = (size_t)NN * 512;
    float* x1s = out;
    float* x2s = out + os;
    float* x1f = out + 2 * os;
    float* x2f = out + 3 * os;

    const int GG = (NN / 64) * 4;

    k_detect<<<1, 64, 0, stream>>>(e_sc);
    k_adj_fused<<<1024, 256, 0, stream>>>(e_sc, e_fc);

    k_convW<<<(256 * (XLD / 8) + 255) / 256, 256, 0, stream>>>(W0, NODE, XLD, 0);
    k_convW<<<(256 * 32 + 255) / 256, 256, 0, stream>>>(Wa, HID, 256, 1);
    k_convW<<<(256 * 64 + 255) / 256, 256, 0, stream>>>(W1, 512, 512, 2);
    k_convX<<<(NN * (XLD / 8) + 255) / 256, 256, 0, stream>>>(x_sc, 0);
    k_convX<<<(NN * (XLD / 8) + 255) / 256, 256, 0, stream>>>(x_fc, 1);

    // ---- layer 1 ----
    k_gemm_mfma<<<GG, 256, 0, stream>>>(4, -1, XLD, XLD, 0, XLD, 0);
    k_gemm_mfma<<<GG, 256, 0, stream>>>(5, -1, XLD, XLD, 0, XLD, NN);
    k_agg2<<<2048, 256, 0, stream>>>(b0, x1s, x1f);

    // ---- co-attention 1 ----
    k_gemm_mfma<<<GG, 256, 0, stream>>>(0, -1, HID, 256, 1, 256, 0);
    k_score_f32<<<NB, CO_THREADS, 0, stream>>>(1);
    k_pv2<<<NB * 2, 256, 0, stream>>>(1, 2, x1s + HID, 1);
    k_pv3<<<NB * 2, 256, 0, stream>>>(0, 3, x1f + HID, 1);

    // ---- layer 2 ----
    k_gemm_mfma<<<GG, 256, 0, stream>>>(0, 2, HID, 512, 2, 512, 0);
    k_gemm_mfma<<<GG, 256, 0, stream>>>(1, 3, HID, 512, 2, 512, NN);
    k_agg2<<<2048, 256, 0, stream>>>(b1, x2s, x2f);

    // ---- co-attention 2 ----
    k_gemm_mfma<<<GG, 256, 0, stream>>>(0, -1, HID, 256, 1, 256, 0);
    k_score_f32<<<NB, CO_THREADS, 0, stream>>>(1);
    k_pv2<<<NB * 2, 256, 0, stream>>>(1, 2, x2s + HID, 0);
    k_pv3<<<NB * 2, 256, 0, stream>>>(0, 3, x2f + HID, 0);
}

// Round 16
// 1107.388 us; speedup vs baseline: 1.3824x; 1.0860x over previous
//
#include <hip/hip_runtime.h>
#include <hip/hip_bf16.h>
#include <math.h>

#define NODE 90
#define HID 256
#define NB 512
#define NN (NB * NODE)
#define EDGES (NB * 2700)
#define XLD 96

typedef __attribute__((ext_vector_type(8))) short bf16x8;
typedef __attribute__((ext_vector_type(4))) float f32x4;

__device__ __forceinline__ float tanh_safe(float s) {
    s = fminf(fmaxf(s, -15.f), 15.f);
    float t = __expf(2.f * s);
    return (t - 1.f) / (t + 1.f);
}
__device__ __forceinline__ unsigned short f2b(float x) {
    unsigned u = __float_as_uint(x);
    return (unsigned short)((u + 0x7FFFu + ((u >> 16) & 1u)) >> 16);
}
__device__ __forceinline__ float b2f(unsigned short h) {
    return __uint_as_float(((unsigned)h) << 16);
}

// ---------------------------------------------------------------------------
__device__ float g_adjS[(size_t)NB * NODE * NODE];
__device__ float g_adjF[(size_t)NB * NODE * NODE];
__device__ float g_T[(size_t)2 * NN * HID];
__device__ float g_hs[(size_t)NN * HID];
__device__ float g_hf[(size_t)NN * HID];
__device__ float g_P[(size_t)NB * NODE * NODE];
__device__ float g_fn[NB * 96];
__device__ float g_gm[NB * 96];
__device__ int g_flags[2];

__device__ unsigned short g_hshi[(size_t)NN * HID], g_hslo[(size_t)NN * HID];
__device__ unsigned short g_hfhi[(size_t)NN * HID], g_hflo[(size_t)NN * HID];
__device__ unsigned short g_cshi[(size_t)NN * HID], g_cslo[(size_t)NN * HID];
__device__ unsigned short g_cfhi[(size_t)NN * HID], g_cflo[(size_t)NN * HID];
__device__ unsigned short g_xshi[(size_t)NN * XLD], g_xslo[(size_t)NN * XLD];
__device__ unsigned short g_xfhi[(size_t)NN * XLD], g_xflo[(size_t)NN * XLD];
__device__ unsigned short g_t2hi[(size_t)NN * HID], g_t2lo[(size_t)NN * HID];
__device__ unsigned short g_w0thi[256 * XLD], g_w0tlo[256 * XLD];
__device__ unsigned short g_wathi[256 * 256], g_watlo[256 * 256];
__device__ unsigned short g_w1thi[256 * 512], g_w1tlo[256 * 512];

__device__ __forceinline__ float* adjPtr(int w) { return w ? g_adjF : g_adjS; }
__device__ __forceinline__ float* selbuf(int w) { return w ? g_hf : g_hs; }
__device__ __forceinline__ unsigned short* selhi(int w) {
    switch (w) {
        case 0: return g_hshi;
        case 1: return g_hfhi;
        case 2: return g_cshi;
        case 3: return g_cfhi;
        case 4: return g_xshi;
        default: return g_xfhi;
    }
}
__device__ __forceinline__ unsigned short* sello(int w) {
    switch (w) {
        case 0: return g_hslo;
        case 1: return g_hflo;
        case 2: return g_cslo;
        case 3: return g_cflo;
        case 4: return g_xslo;
        default: return g_xflo;
    }
}
__device__ __forceinline__ unsigned short* wthi(int w) {
    switch (w) { case 0: return g_w0thi; case 1: return g_wathi; default: return g_w1thi; }
}
__device__ __forceinline__ unsigned short* wtlo(int w) {
    switch (w) { case 0: return g_w0tlo; case 1: return g_watlo; default: return g_w1tlo; }
}

// ---------------------------------------------------------------------------
__global__ void k_detect(const void* edges) {
    if (threadIdx.x != 0 || blockIdx.x != 0) return;
    const int* ei = (const int*)edges;
    int odd_nonzero = 0;
    for (int i = 0; i < 2048; i += 2)
        if (ei[i + 1] != 0) odd_nonzero = 1;
    g_flags[1] = odd_nonzero ? 0 : 1;
}

// ---------------------------------------------------------------------------
__global__ __launch_bounds__(256) void k_adj_fused(const void* __restrict__ eS,
                                                   const void* __restrict__ eF) {
    __shared__ float cnt[NODE][NODE + 1];
    __shared__ float dinv[NODE];
    int side = blockIdx.x >> 9;
    int b = blockIdx.x & 511;
    const void* edges = side ? eF : eS;
    int tid = threadIdx.x;
    for (int i = tid; i < NODE * (NODE + 1); i += 256) (&cnt[0][0])[i] = 0.f;
    __syncthreads();
    int e64 = g_flags[1];
    const long long* p64 = (const long long*)edges;
    const int* p32 = (const int*)edges;
    for (int i = tid; i < 2700; i += 256) {
        int idx = b * 2700 + i;
        long long s, d;
        if (e64) { s = p64[idx]; d = p64[EDGES + idx]; }
        else     { s = p32[idx]; d = p32[EDGES + idx]; }
        int sl = (int)s - b * NODE, dl = (int)d - b * NODE;
        if (sl >= 0 && sl < NODE && dl >= 0 && dl < NODE)
            atomicAdd(&cnt[dl][sl], 1.0f);
    }
    __syncthreads();
    if (tid < NODE) {
        float s = 0.f;
        for (int k = 0; k < NODE; k++) s += cnt[tid][k];
        dinv[tid] = (s > 0.f) ? rsqrtf(s) : 0.f;
    }
    __syncthreads();
    float* adj = adjPtr(side) + (size_t)b * NODE * NODE;
    for (int i = tid; i < NODE * NODE; i += 256) {
        int d = i / NODE, s = i - d * NODE;
        adj[i] = cnt[d][s] * dinv[d] * dinv[s];
    }
}

// ---------------------------------------------------------------------------
__global__ void k_convX(const float* __restrict__ X, int side) {
    int t = blockIdx.x * blockDim.x + threadIdx.x;
    if (t >= NN * (XLD / 8)) return;
    int r = t / (XLD / 8), o = t - r * (XLD / 8);
    unsigned short h8[8], l8[8];
#pragma unroll
    for (int j = 0; j < 8; j++) {
        int k = 8 * o + j;
        float x = (k < NODE) ? X[(size_t)r * NODE + k] : 0.f;
        unsigned short h = f2b(x);
        h8[j] = h;
        l8[j] = f2b(x - b2f(h));
    }
    unsigned short* ph = side ? g_xfhi : g_xshi;
    unsigned short* pl = side ? g_xflo : g_xslo;
    *(uint4*)&ph[(size_t)r * XLD + 8 * o] = *(uint4*)h8;
    *(uint4*)&pl[(size_t)r * XLD + 8 * o] = *(uint4*)l8;
}

__global__ void k_convW(const float* __restrict__ W, int K, int Kpad, int which) {
    int t = blockIdx.x * blockDim.x + threadIdx.x;
    if (t >= 256 * (Kpad / 8)) return;
    int c = t / (Kpad / 8), o = t - c * (Kpad / 8);
    unsigned short h8[8], l8[8];
#pragma unroll
    for (int j = 0; j < 8; j++) {
        int k = 8 * o + j;
        float x = (k < K) ? W[(size_t)k * 256 + c] : 0.f;
        unsigned short h = f2b(x);
        h8[j] = h;
        l8[j] = f2b(x - b2f(h));
    }
    *(uint4*)&wthi(which)[(size_t)c * Kpad + 8 * o] = *(uint4*)h8;
    *(uint4*)&wtlo(which)[(size_t)c * Kpad + 8 * o] = *(uint4*)l8;
}

// ---------------------------------------------------------------------------
// MFMA bf16x2-split GEMM from planes. emitT2=1: write hi/lo planes (g_t2*)
// instead of fp32 g_T (used for the Wa GEMM feeding the MFMA score kernel).
// ---------------------------------------------------------------------------
#define GK 32
#define ASTR 40
__global__ __launch_bounds__(256) void k_gemm_mfma(int xsel, int x2sel, int kld,
                                                   int K, int wsel, int wld,
                                                   int tbase, int emitT2) {
    __shared__ unsigned short Ah[64][ASTR], Al[64][ASTR];
    __shared__ unsigned short Bh[64][ASTR], Bl[64][ASTR];
    int tid = threadIdx.x;
    int id = blockIdx.x;
    int bn = id & 3, bm = id >> 2;
    int r0 = bm * 64, c0 = bn * 64;
    const unsigned short* whi_ = wthi(wsel);
    const unsigned short* wlo_ = wtlo(wsel);

    int w = tid >> 6;
    int l = tid & 63;
    int lr = l & 15;
    int lq = l >> 4;
    int koff = lq * 8;
    int sr = tid >> 2, so = (tid & 3) * 8;

    f32x4 acc[4];
#pragma unroll
    for (int c = 0; c < 4; c++) acc[c] = (f32x4){0.f, 0.f, 0.f, 0.f};

    int nt = K / GK;
    for (int t = 0; t < nt; t++) {
        int k0 = t * GK;
        const unsigned short *phi, *plo;
        int xc;
        if (x2sel >= 0 && k0 >= HID) { phi = selhi(x2sel); plo = sello(x2sel); xc = k0 - HID; }
        else                          { phi = selhi(xsel);  plo = sello(xsel);  xc = k0; }

        __syncthreads();
        {
            size_t ga = (size_t)(r0 + sr) * kld + xc + so;
            *(uint4*)&Ah[sr][so] = *(const uint4*)&phi[ga];
            *(uint4*)&Al[sr][so] = *(const uint4*)&plo[ga];
            size_t gb = (size_t)(c0 + sr) * wld + k0 + so;
            *(uint4*)&Bh[sr][so] = *(const uint4*)&whi_[gb];
            *(uint4*)&Bl[sr][so] = *(const uint4*)&wlo_[gb];
        }
        __syncthreads();

        bf16x8 ah = *(const bf16x8*)&Ah[16 * w + lr][koff];
        bf16x8 al = *(const bf16x8*)&Al[16 * w + lr][koff];
#pragma unroll
        for (int c = 0; c < 4; c++) {
            bf16x8 bh = *(const bf16x8*)&Bh[16 * c + lr][koff];
            bf16x8 bl = *(const bf16x8*)&Bl[16 * c + lr][koff];
            acc[c] = __builtin_amdgcn_mfma_f32_16x16x32_bf16(ah, bh, acc[c], 0, 0, 0);
            acc[c] = __builtin_amdgcn_mfma_f32_16x16x32_bf16(ah, bl, acc[c], 0, 0, 0);
            acc[c] = __builtin_amdgcn_mfma_f32_16x16x32_bf16(al, bh, acc[c], 0, 0, 0);
        }
    }

#pragma unroll
    for (int c = 0; c < 4; c++) {
#pragma unroll
        for (int qq = 0; qq < 4; qq++) {
            size_t row = (size_t)(tbase + r0 + 16 * w + 4 * lq + qq);
            size_t col = c0 + 16 * c + lr;
            float v = acc[c][qq];
            if (emitT2) {
                unsigned short h = f2b(v);
                g_t2hi[row * HID + col] = h;
                g_t2lo[row * HID + col] = f2b(v - b2f(h));
            } else {
                g_T[row * HID + col] = v;
            }
        }
    }
}

// ---------------------------------------------------------------------------
// Fused two-stream aggregate; emits h fp32 + hi/lo planes. (validated)
// ---------------------------------------------------------------------------
__global__ __launch_bounds__(256) void k_agg2(const float* __restrict__ bias,
                                              float* __restrict__ outS,
                                              float* __restrict__ outF) {
    __shared__ float AdjT[NODE][102];
    int tid = threadIdx.x;
    int idx = blockIdx.x;
    int side = idx >> 10;
    int b = (idx & 1023) >> 1;
    int c0 = (idx & 1) * 128;
    const float* Adj = adjPtr(side) + (size_t)b * NODE * NODE;
    const float* Tg = g_T + ((size_t)side * NN + (size_t)b * NODE) * HID;
    float* outp = side ? outF : outS;
    float* hdst = selbuf(side);
    unsigned short* phD = selhi(side);
    unsigned short* plD = sello(side);

    for (int i = tid; i < NODE * NODE; i += 256) {
        int n = i / NODE, k = i - n * NODE;
        AdjT[k][n] = Adj[i];
    }
    for (int i = tid; i < NODE * 12; i += 256) {
        int k = i / 12, n = NODE + (i % 12);
        AdjT[k][n] = 0.f;
    }
    __syncthreads();

    int ti = tid & 15, tj = tid >> 4;
    int rbase = 6 * ti;
    int cc = c0 + 8 * tj;

    float acc[6][8];
#pragma unroll
    for (int i = 0; i < 6; i++)
#pragma unroll
        for (int j = 0; j < 8; j++) acc[i][j] = 0.f;

#pragma unroll 2
    for (int k = 0; k < NODE; k++) {
        float4 t0 = *(const float4*)&Tg[(size_t)k * HID + cc];
        float4 t1 = *(const float4*)&Tg[(size_t)k * HID + cc + 4];
        float bv[8] = {t0.x, t0.y, t0.z, t0.w, t1.x, t1.y, t1.z, t1.w};
        float2 a01 = *(const float2*)&AdjT[k][rbase];
        float2 a23 = *(const float2*)&AdjT[k][rbase + 2];
        float2 a45 = *(const float2*)&AdjT[k][rbase + 4];
        float av[6] = {a01.x, a01.y, a23.x, a23.y, a45.x, a45.y};
#pragma unroll
        for (int i = 0; i < 6; i++)
#pragma unroll
            for (int j = 0; j < 8; j++)
                acc[i][j] = fmaf(av[i], bv[j], acc[i][j]);
    }

    float bb[8];
#pragma unroll
    for (int j = 0; j < 8; j++) bb[j] = bias[cc + j];

#pragma unroll
    for (int i = 0; i < 6; i++) {
        int n = rbase + i;
        if (n < NODE) {
            size_t row = (size_t)(b * NODE + n);
            float v[8];
            unsigned short h8[8], l8[8];
#pragma unroll
            for (int j = 0; j < 8; j++) {
                v[j] = fmaxf(acc[i][j] + bb[j], 0.f);
                unsigned short h = f2b(v[j]);
                h8[j] = h;
                l8[j] = f2b(v[j] - b2f(h));
            }
            float4 o0 = make_float4(v[0], v[1], v[2], v[3]);
            float4 o1 = make_float4(v[4], v[5], v[6], v[7]);
            *(float4*)&hdst[row * HID + cc] = o0;
            *(float4*)&hdst[row * HID + cc + 4] = o1;
            *(float4*)&outp[row * 512 + cc] = o0;
            *(float4*)&outp[row * 512 + cc + 4] = o1;
            *(uint4*)&phD[row * HID + cc] = *(uint4*)h8;
            *(uint4*)&plD[row * HID + cc] = *(uint4*)l8;
        }
    }
}

// ---------------------------------------------------------------------------
// Scores via MFMA (r14 structure + OOB FIX): At = tanh(T2 @ HF^T), K=256,
// 96x96 padded tile, 2x2 waves x 48x48. Pm writes GUARDED to col<92.
// Then softmax stats; P = row-softmax(At) -> g_P; fn/gm -> global.
// ---------------------------------------------------------------------------
__global__ __launch_bounds__(256) void k_score_mfma(int hfsel) {
    __shared__ unsigned short Ah[96][ASTR], Al[96][ASTR];
    __shared__ unsigned short Bh[96][ASTR], Bl[96][ASTR];
    __shared__ float Pm[96][92];
    __shared__ float rmax_[96], rinv_[96], fn_[96], gm_[96];

    int b = blockIdx.x;
    int tid = threadIdx.x;
    const unsigned short* t2h = g_t2hi + (size_t)b * NODE * HID;
    const unsigned short* t2l = g_t2lo + (size_t)b * NODE * HID;
    const unsigned short* hfh = selhi(hfsel) + (size_t)b * NODE * HID;
    const unsigned short* hfl_ = sello(hfsel) + (size_t)b * NODE * HID;

    int w = tid >> 6, l = tid & 63;
    int lr = l & 15, lq = l >> 4, koff = 8 * lq;
    int wr = w >> 1, wc = w & 1;

    f32x4 acc[3][3];
#pragma unroll
    for (int i = 0; i < 3; i++)
#pragma unroll
        for (int j = 0; j < 3; j++) acc[i][j] = (f32x4){0.f, 0.f, 0.f, 0.f};

    const uint4 z4 = make_uint4(0, 0, 0, 0);
    for (int t = 0; t < 8; t++) {
        int k0 = 32 * t;
        __syncthreads();
        for (int i = tid; i < 96 * 4; i += 256) {
            int r = i >> 2, o = (i & 3) << 3;
            uint4 vah = z4, val = z4, vbh = z4, vbl = z4;
            if (r < NODE) {
                size_t g = (size_t)r * HID + k0 + o;
                vah = *(const uint4*)&t2h[g];
                val = *(const uint4*)&t2l[g];
                vbh = *(const uint4*)&hfh[g];
                vbl = *(const uint4*)&hfl_[g];
            }
            *(uint4*)&Ah[r][o] = vah;
            *(uint4*)&Al[r][o] = val;
            *(uint4*)&Bh[r][o] = vbh;
            *(uint4*)&Bl[r][o] = vbl;
        }
        __syncthreads();

        bf16x8 ah[3], al[3], bh[3], bl[3];
#pragma unroll
        for (int i = 0; i < 3; i++) {
            ah[i] = *(const bf16x8*)&Ah[48 * wr + 16 * i + lr][koff];
            al[i] = *(const bf16x8*)&Al[48 * wr + 16 * i + lr][koff];
            bh[i] = *(const bf16x8*)&Bh[48 * wc + 16 * i + lr][koff];
            bl[i] = *(const bf16x8*)&Bl[48 * wc + 16 * i + lr][koff];
        }
#pragma unroll
        for (int i = 0; i < 3; i++)
#pragma unroll
            for (int j = 0; j < 3; j++) {
                acc[i][j] = __builtin_amdgcn_mfma_f32_16x16x32_bf16(ah[i], bh[j], acc[i][j], 0, 0, 0);
                acc[i][j] = __builtin_amdgcn_mfma_f32_16x16x32_bf16(ah[i], bl[j], acc[i][j], 0, 0, 0);
                acc[i][j] = __builtin_amdgcn_mfma_f32_16x16x32_bf16(al[i], bh[j], acc[i][j], 0, 0, 0);
            }
    }

#pragma unroll
    for (int i = 0; i < 3; i++)
#pragma unroll
        for (int j = 0; j < 3; j++)
#pragma unroll
            for (int qq = 0; qq < 4; qq++) {
                int row = 48 * wr + 16 * i + 4 * lq + qq;
                int col = 48 * wc + 16 * j + lr;
                if (col < 92)                       // OOB fix (was r14's bug)
                    Pm[row][col] = tanh_safe(acc[i][j][qq]);
            }
    __syncthreads();

    if (tid < NODE) {
        int n = tid;
        float mx = -2.f;
        for (int m = 0; m < NODE; m++) mx = fmaxf(mx, Pm[n][m]);
        float s = 0.f;
        for (int m = 0; m < NODE; m++) s += __expf(Pm[n][m] - mx);
        rmax_[n] = mx;
        rinv_[n] = 1.f / s;
        fn_[n] = s * __expf(mx);
    } else if (tid >= 128 && tid < 128 + NODE) {
        int m = tid - 128;
        float mx = -2.f;
        for (int n = 0; n < NODE; n++) mx = fmaxf(mx, Pm[n][m]);
        float s = 0.f;
        for (int n = 0; n < NODE; n++) s += __expf(Pm[n][m] - mx);
        gm_[m] = __expf(-mx) / s;
    }
    __syncthreads();

    float* Pg = g_P + (size_t)b * NODE * NODE;
    for (int i = tid; i < NODE * NODE; i += 256) {
        int n = i / NODE, m = i - n * NODE;
        Pg[i] = __expf(Pm[n][m] - rmax_[n]) * rinv_[n];
    }
    if (tid < NODE) {
        g_fn[b * 96 + tid] = fn_[tid];
        g_gm[b * 96 + tid] = gm_[tid];
    }
}

// ---------------------------------------------------------------------------
// co_s = P @ HF (half-width panel per block). grid = NB*2.
// ---------------------------------------------------------------------------
__global__ __launch_bounds__(256) void k_pv2(int fsel, int cssel,
                                             float* __restrict__ outp, int emit) {
    __shared__ float Pl[NODE][91];
    __shared__ float Hl[NODE][129];
    int b = blockIdx.x >> 1;
    int c0 = (blockIdx.x & 1) * 128;
    int tid = threadIdx.x;
    const float* Pg = g_P + (size_t)b * NODE * NODE;
    for (int i = tid; i < NODE * NODE; i += 256) {
        int n = i / NODE, m = i - n * NODE;
        Pl[n][m] = Pg[i];
    }
    const float* H = selbuf(fsel) + (size_t)b * NODE * HID;
    for (int i = tid; i < NODE * 32; i += 256) {
        int r = i >> 5, c4 = (i & 31) << 2;
        *(float4*)&Hl[r][c4] = *(const float4*)&H[(size_t)r * HID + c0 + c4];
    }
    __syncthreads();

    int c4 = (tid & 31) << 2;
    int rg = tid >> 5;
    float acc[12][4];
#pragma unroll
    for (int k = 0; k < 12; k++)
#pragma unroll
        for (int j = 0; j < 4; j++) acc[k][j] = 0.f;

#pragma unroll 2
    for (int m = 0; m < NODE; m++) {
        float4 h = *(const float4*)&Hl[m][c4];
#pragma unroll
        for (int k = 0; k < 12; k++) {
            int n = rg + 8 * k;
            float p = Pl[(n < NODE) ? n : 0][m];
            acc[k][0] = fmaf(p, h.x, acc[k][0]);
            acc[k][1] = fmaf(p, h.y, acc[k][1]);
            acc[k][2] = fmaf(p, h.z, acc[k][2]);
            acc[k][3] = fmaf(p, h.w, acc[k][3]);
        }
    }

    unsigned short* csh = selhi(cssel);
    unsigned short* csl = sello(cssel);
#pragma unroll
    for (int k = 0; k < 12; k++) {
        int n = rg + 8 * k;
        if (n < NODE) {
            size_t row = (size_t)(b * NODE + n);
            size_t gc = c0 + c4;
            *(float4*)&outp[row * 512 + gc] =
                make_float4(acc[k][0], acc[k][1], acc[k][2], acc[k][3]);
            if (emit) {
                unsigned short h4[4], l4[4];
#pragma unroll
                for (int j = 0; j < 4; j++) {
                    unsigned short h = f2b(acc[k][j]);
                    h4[j] = h;
                    l4[j] = f2b(acc[k][j] - b2f(h));
                }
                *(uint2*)&csh[row * HID + gc] = *(uint2*)h4;
                *(uint2*)&csl[row * HID + gc] = *(uint2*)l4;
            }
        }
    }
}

// ---------------------------------------------------------------------------
// co_f[m] = gm[m] * Σ_n (P[n][m]*fn[n]) * HS[n]. grid = NB*2.
// ---------------------------------------------------------------------------
__global__ __launch_bounds__(256) void k_pv3(int ssel, int cfsel,
                                             float* __restrict__ outp, int emit) {
    __shared__ float Pl[NODE][91];
    __shared__ float Hl[NODE][129];
    __shared__ float fnl[96], gml[96];
    int b = blockIdx.x >> 1;
    int c0 = (blockIdx.x & 1) * 128;
    int tid = threadIdx.x;
    const float* Pg = g_P + (size_t)b * NODE * NODE;
    for (int i = tid; i < NODE * NODE; i += 256) {
        int n = i / NODE, m = i - n * NODE;
        Pl[n][m] = Pg[i];
    }
    const float* H = selbuf(ssel) + (size_t)b * NODE * HID;
    for (int i = tid; i < NODE * 32; i += 256) {
        int r = i >> 5, c4 = (i & 31) << 2;
        *(float4*)&Hl[r][c4] = *(const float4*)&H[(size_t)r * HID + c0 + c4];
    }
    if (tid < 96) {
        fnl[tid] = (tid < NODE) ? g_fn[b * 96 + tid] : 0.f;
        gml[tid] = (tid < NODE) ? g_gm[b * 96 + tid] : 0.f;
    }
    __syncthreads();

    int c4 = (tid & 31) << 2;
    int rg = tid >> 5;
    float acc[12][4];
#pragma unroll
    for (int k = 0; k < 12; k++)
#pragma unroll
        for (int j = 0; j < 4; j++) acc[k][j] = 0.f;

#pragma unroll 2
    for (int n = 0; n < NODE; n++) {
        float4 h = *(const float4*)&Hl[n][c4];
        float f = fnl[n];
#pragma unroll
        for (int k = 0; k < 12; k++) {
            int m = rg + 8 * k;
            float p = Pl[n][(m < NODE) ? m : 0] * f;
            acc[k][0] = fmaf(p, h.x, acc[k][0]);
            acc[k][1] = fmaf(p, h.y, acc[k][1]);
            acc[k][2] = fmaf(p, h.z, acc[k][2]);
            acc[k][3] = fmaf(p, h.w, acc[k][3]);
        }
    }

    unsigned short* cfh = selhi(cfsel);
    unsigned short* cfl = sello(cfsel);
#pragma unroll
    for (int k = 0; k < 12; k++) {
        int m = rg + 8 * k;
        if (m < NODE) {
            float g = gml[m];
            size_t row = (size_t)(b * NODE + m);
            size_t gc = c0 + c4;
            float o4[4] = {acc[k][0] * g, acc[k][1] * g, acc[k][2] * g, acc[k][3] * g};
            *(float4*)&outp[row * 512 + gc] = make_float4(o4[0], o4[1], o4[2], o4[3]);
            if (emit) {
                unsigned short h4[4], l4[4];
#pragma unroll
                for (int j = 0; j < 4; j++) {
                    unsigned short h = f2b(o4[j]);
                    h4[j] = h;
                    l4[j] = f2b(o4[j] - b2f(h));
                }
                *(uint2*)&cfh[row * HID + gc] = *(uint2*)h4;
                *(uint2*)&cfl[row * HID + gc] = *(uint2*)l4;
            }
        }
    }
}

// ---------------------------------------------------------------------------
extern "C" void kernel_launch(void* const* d_in, const int* in_sizes, int n_in,
                              void* d_out, int out_size, void* d_ws, size_t ws_size,
                              hipStream_t stream) {
    const float* x_sc = (const float*)d_in[0];
    const void* e_sc = d_in[1];
    const float* x_fc = (const float*)d_in[2];
    const void* e_fc = d_in[3];
    const float* W0 = (const float*)d_in[4];
    const float* b0 = (const float*)d_in[5];
    const float* W1 = (const float*)d_in[6];
    const float* b1 = (const float*)d_in[7];
    const float* Wa = (const float*)d_in[8];

    float* out = (float*)d_out;
    size_t os = (size_t)NN * 512;
    float* x1s = out;
    float* x2s = out + os;
    float* x1f = out + 2 * os;
    float* x2f = out + 3 * os;

    const int GG = (NN / 64) * 4;

    k_detect<<<1, 64, 0, stream>>>(e_sc);
    k_adj_fused<<<1024, 256, 0, stream>>>(e_sc, e_fc);

    k_convW<<<(256 * (XLD / 8) + 255) / 256, 256, 0, stream>>>(W0, NODE, XLD, 0);
    k_convW<<<(256 * 32 + 255) / 256, 256, 0, stream>>>(Wa, HID, 256, 1);
    k_convW<<<(256 * 64 + 255) / 256, 256, 0, stream>>>(W1, 512, 512, 2);
    k_convX<<<(NN * (XLD / 8) + 255) / 256, 256, 0, stream>>>(x_sc, 0);
    k_convX<<<(NN * (XLD / 8) + 255) / 256, 256, 0, stream>>>(x_fc, 1);

    // ---- layer 1 ----
    k_gemm_mfma<<<GG, 256, 0, stream>>>(4, -1, XLD, XLD, 0, XLD, 0, 0);
    k_gemm_mfma<<<GG, 256, 0, stream>>>(5, -1, XLD, XLD, 0, XLD, NN, 0);
    k_agg2<<<2048, 256, 0, stream>>>(b0, x1s, x1f);

    // ---- co-attention 1 ----
    k_gemm_mfma<<<GG, 256, 0, stream>>>(0, -1, HID, 256, 1, 256, 0, 1);
    k_score_mfma<<<NB, 256, 0, stream>>>(1);
    k_pv2<<<NB * 2, 256, 0, stream>>>(1, 2, x1s + HID, 1);
    k_pv3<<<NB * 2, 256, 0, stream>>>(0, 3, x1f + HID, 1);

    // ---- layer 2 ----
    k_gemm_mfma<<<GG, 256, 0, stream>>>(0, 2, HID, 512, 2, 512, 0, 0);
    k_gemm_mfma<<<GG, 256, 0, stream>>>(1, 3, HID, 512, 2, 512, NN, 0);
    k_agg2<<<2048, 256, 0, stream>>>(b1, x2s, x2f);

    // ---- co-attention 2 ----
    k_gemm_mfma<<<GG, 256, 0, stream>>>(0, -1, HID, 256, 1, 256, 0, 1);
    k_score_mfma<<<NB, 256, 0, stream>>>(1);
    k_pv2<<<NB * 2, 256, 0, stream>>>(1, 2, x2s + HID, 0);
    k_pv3<<<NB * 2, 256, 0, stream>>>(0, 3, x2f + HID, 0);
}